// Round 1
// baseline (2148.862 us; speedup 1.0000x reference)
//
#include <hip/hip_runtime.h>
#include <hip/hip_bf16.h>

// Problem constants (B=4, S=2048, D_MODEL=1024, H=16, DH=64, RANK=256, NPRIM=16, top_k=4)
#define TOK    8192          // B*S
#define SEQ    2048
#define NHEAD  16
#define NT_ELE 8388608       // TOK*1024

// ---------------------------------------------------------------------------
// Top-4 selection: softmax->top_k->renorm == softmax over top-4 logits (exact)
// ---------------------------------------------------------------------------
__global__ void topk_kernel(const float* __restrict__ ql, const float* __restrict__ kl,
                            const float* __restrict__ vl, const float* __restrict__ gl,
                            int* __restrict__ sel_idx, float* __restrict__ sel_w)
{
    const int p = threadIdx.x;
    if (p >= 4) return;
    const float* lg = (p == 0) ? ql : (p == 1) ? kl : (p == 2) ? vl : gl;
    float v[16];
    for (int i = 0; i < 16; i++) v[i] = lg[i];
    bool used[16];
    for (int i = 0; i < 16; i++) used[i] = false;
    int idx[4]; float val[4];
    for (int k = 0; k < 4; k++) {
        int bi = -1; float bv = -__builtin_inff();
        for (int i = 0; i < 16; i++)
            if (!used[i] && v[i] > bv) { bv = v[i]; bi = i; }
        used[bi] = true; idx[k] = bi; val[k] = bv;
    }
    const float m = val[0];           // top-1, sorted descending
    float e[4], s = 0.f;
    for (int k = 0; k < 4; k++) { e[k] = expf(val[k] - m); s += e[k]; }
    for (int k = 0; k < 4; k++) { sel_idx[p*4 + k] = idx[k]; sel_w[p*4 + k] = e[k] / s; }
}

// ---------------------------------------------------------------------------
// W_eff builder: W_eff_p[d,o] = sum_k w_k * U[idx_k][d,:] @ V[idx_k][:,o]
// M=N=K=1024, gathered A (U) and B (V) by k-block of 256, w folded into A.
// ---------------------------------------------------------------------------
__global__ __launch_bounds__(256)
void weff_kernel(const float* __restrict__ qU, const float* __restrict__ kU, const float* __restrict__ vU,
                 const float* __restrict__ qV, const float* __restrict__ kV, const float* __restrict__ vV,
                 float* __restrict__ Wout,
                 const int* __restrict__ sel_idx_all, const float* __restrict__ sel_w_all)
{
    const int p = blockIdx.z;
    const float* U = (p == 0) ? qU : (p == 1) ? kU : vU;
    const float* V = (p == 0) ? qV : (p == 1) ? kV : vV;
    const int*   si = sel_idx_all + p*4;
    const float* sw = sel_w_all  + p*4;
    float* C = Wout + (size_t)p * 1024 * 1024;

    __shared__ float As[8][132];
    __shared__ float Bs[8][132];
    const int tid = threadIdx.x;
    const int n0 = blockIdx.x * 128, m0 = blockIdx.y * 128;
    const int tx = tid & 15, ty = tid >> 4;
    const int ar = tid >> 1,  ac  = (tid & 1) << 2;
    const int bnr = tid >> 5, bnc = (tid & 31) << 2;

    int prim[4]; float wsel[4];
    #pragma unroll
    for (int i = 0; i < 4; i++) { prim[i] = si[i]; wsel[i] = sw[i]; }

    float acc[8][8]{};
    for (int k0 = 0; k0 < 1024; k0 += 8) {
        const int blk = k0 >> 8;
        const float* Ub = U + (size_t)prim[blk] * (1024 * 256);
        const float* Vb = V + (size_t)prim[blk] * (256 * 1024);
        const float wv = wsel[blk];
        float4 a4 = *(const float4*)(Ub + (size_t)(m0 + ar) * 256 + (k0 & 255) + ac);
        a4.x *= wv; a4.y *= wv; a4.z *= wv; a4.w *= wv;
        float4 b4 = *(const float4*)(Vb + (size_t)((k0 & 255) + bnr) * 1024 + n0 + bnc);
        __syncthreads();
        As[ac+0][ar] = a4.x; As[ac+1][ar] = a4.y; As[ac+2][ar] = a4.z; As[ac+3][ar] = a4.w;
        *(float4*)&Bs[bnr][bnc] = b4;
        __syncthreads();
        #pragma unroll
        for (int kk = 0; kk < 8; kk++) {
            float av[8], bv[8];
            *(float4*)&av[0] = *(const float4*)&As[kk][ty*8];
            *(float4*)&av[4] = *(const float4*)&As[kk][ty*8 + 4];
            *(float4*)&bv[0] = *(const float4*)&Bs[kk][tx*8];
            *(float4*)&bv[4] = *(const float4*)&Bs[kk][tx*8 + 4];
            #pragma unroll
            for (int i = 0; i < 8; i++)
                #pragma unroll
                for (int j = 0; j < 8; j++)
                    acc[i][j] = fmaf(av[i], bv[j], acc[i][j]);
        }
    }
    #pragma unroll
    for (int i = 0; i < 8; i++) {
        float* cr = C + (size_t)(m0 + ty*8 + i) * 1024 + n0 + tx*8;
        *(float4*)cr       = make_float4(acc[i][0], acc[i][1], acc[i][2], acc[i][3]);
        *(float4*)(cr + 4) = make_float4(acc[i][4], acc[i][5], acc[i][6], acc[i][7]);
    }
}

// ---------------------------------------------------------------------------
// Generic 128x128x8 fp32 GEMM, M=8192, N=K=1024. MODE 0: C=A@B (B row-major
// KxN). MODE 1: C=A@B^T layout (B is [N,K] row-major, i.e. C[m,n]=sum A[m,k]*B[n,k]).
// blockIdx.z strides B by bz and C by cz (to batch the 4 projections).
// ---------------------------------------------------------------------------
template<int MODE>
__global__ __launch_bounds__(256)
void gemm128(const float* __restrict__ A, const float* __restrict__ Bsrc,
             float* __restrict__ Cdst, size_t bz, size_t cz)
{
    const float* B = Bsrc + (size_t)blockIdx.z * bz;
    float* C = Cdst + (size_t)blockIdx.z * cz;
    __shared__ float As[8][132];
    __shared__ float Bs[8][132];
    const int tid = threadIdx.x;
    const int n0 = blockIdx.x * 128, m0 = blockIdx.y * 128;
    const int tx = tid & 15, ty = tid >> 4;
    const int ar = tid >> 1,  ac  = (tid & 1) << 2;
    const int bnr = tid >> 5, bnc = (tid & 31) << 2;  // MODE 0
    const int btn = tid >> 1, btk = (tid & 1) << 2;   // MODE 1

    float acc[8][8]{};
    for (int k0 = 0; k0 < 1024; k0 += 8) {
        float4 a4 = *(const float4*)(A + (size_t)(m0 + ar) * 1024 + k0 + ac);
        float4 b4;
        if (MODE == 0) b4 = *(const float4*)(B + (size_t)(k0 + bnr) * 1024 + n0 + bnc);
        else           b4 = *(const float4*)(B + (size_t)(n0 + btn) * 1024 + k0 + btk);
        __syncthreads();
        As[ac+0][ar] = a4.x; As[ac+1][ar] = a4.y; As[ac+2][ar] = a4.z; As[ac+3][ar] = a4.w;
        if (MODE == 0) {
            *(float4*)&Bs[bnr][bnc] = b4;
        } else {
            Bs[btk+0][btn] = b4.x; Bs[btk+1][btn] = b4.y;
            Bs[btk+2][btn] = b4.z; Bs[btk+3][btn] = b4.w;
        }
        __syncthreads();
        #pragma unroll
        for (int kk = 0; kk < 8; kk++) {
            float av[8], bv[8];
            *(float4*)&av[0] = *(const float4*)&As[kk][ty*8];
            *(float4*)&av[4] = *(const float4*)&As[kk][ty*8 + 4];
            *(float4*)&bv[0] = *(const float4*)&Bs[kk][tx*8];
            *(float4*)&bv[4] = *(const float4*)&Bs[kk][tx*8 + 4];
            #pragma unroll
            for (int i = 0; i < 8; i++)
                #pragma unroll
                for (int j = 0; j < 8; j++)
                    acc[i][j] = fmaf(av[i], bv[j], acc[i][j]);
        }
    }
    #pragma unroll
    for (int i = 0; i < 8; i++) {
        float* cr = C + (size_t)(m0 + ty*8 + i) * 1024 + n0 + tx*8;
        *(float4*)cr       = make_float4(acc[i][0], acc[i][1], acc[i][2], acc[i][3]);
        *(float4*)(cr + 4) = make_float4(acc[i][4], acc[i][5], acc[i][6], acc[i][7]);
    }
}

// ---------------------------------------------------------------------------
// Per-(token,head) decay: dec = exp(-softplus(x.dw+b)) = sigmoid(-(z)) = 1/(1+e^z)
// ---------------------------------------------------------------------------
__global__ __launch_bounds__(256)
void decay_kernel(const float* __restrict__ x, const float* __restrict__ dw,
                  const float* __restrict__ db, float* __restrict__ dec)
{
    const int gid = blockIdx.x * 256 + threadIdx.x;
    const int t = gid >> 4, h = gid & 15;
    const float4* xr = (const float4*)(x + (size_t)t * 1024);
    const float4* wr = (const float4*)(dw + (size_t)h * 1024);
    float s = 0.f;
    #pragma unroll 4
    for (int i = 0; i < 256; i++) {
        const float4 a = xr[i], b = wr[i];
        s = fmaf(a.x, b.x, fmaf(a.y, b.y, fmaf(a.z, b.z, fmaf(a.w, b.w, s))));
    }
    const float z = s + db[h];
    dec[gid] = 1.0f / (1.0f + expf(z));
}

// ---------------------------------------------------------------------------
// Sequential decay-gated scan, one thread per (b,h,d) lane.
// s_t = a_t * s_{t-1} + sigmoid(g)*k*v ;  out_t = q_t * s_t
// ---------------------------------------------------------------------------
__global__ __launch_bounds__(64)
void scan_kernel(const float* __restrict__ q, const float* __restrict__ k,
                 const float* __restrict__ v, const float* __restrict__ g,
                 const float* __restrict__ dec, float* __restrict__ out)
{
    const int bh = blockIdx.x;
    const int b = bh >> 4, h = bh & 15;
    const size_t base = (size_t)b * SEQ * 1024 + h * 64 + threadIdx.x;
    const float* qp = q + base;
    const float* kp = k + base;
    const float* vp = v + base;
    const float* gp = g + base;
    float* op = out + base;
    const float* dp = dec + (size_t)b * SEQ * 16 + h;
    float s = 0.f;
    #pragma unroll 4
    for (int t = 0; t < SEQ; t++) {
        const size_t off = (size_t)t * 1024;
        const float a  = dp[(size_t)t * 16];
        const float gg = gp[off];
        const float kv = kp[off] * vp[off] * (1.f / (1.f + expf(-gg)));
        s = fmaf(a, s, kv);
        op[off] = qp[off] * s;
    }
}

// ---------------------------------------------------------------------------
// RMSNorm * rms_w * sigmoid(gpre), one block per token
// ---------------------------------------------------------------------------
__global__ __launch_bounds__(256)
void rms_gate_kernel(const float* __restrict__ att, const float* __restrict__ gpre,
                     const float* __restrict__ rmsw, float* __restrict__ o)
{
    const size_t t = blockIdx.x;
    const int tid = threadIdx.x;
    const float4 a = ((const float4*)(att + t * 1024))[tid];
    float ss = a.x*a.x + a.y*a.y + a.z*a.z + a.w*a.w;
    #pragma unroll
    for (int d = 32; d > 0; d >>= 1) ss += __shfl_down(ss, d);
    __shared__ float red[4];
    if ((tid & 63) == 0) red[tid >> 6] = ss;
    __syncthreads();
    const float tot = red[0] + red[1] + red[2] + red[3];
    const float scale = rsqrtf(tot * (1.0f / 1024.0f) + 1.1920929e-7f);
    const float4 gv = ((const float4*)(gpre + t * 1024))[tid];
    const float4 w  = ((const float4*)rmsw)[tid];
    float4 r;
    r.x = a.x * scale * w.x * (1.f / (1.f + expf(-gv.x)));
    r.y = a.y * scale * w.y * (1.f / (1.f + expf(-gv.y)));
    r.z = a.z * scale * w.z * (1.f / (1.f + expf(-gv.z)));
    r.w = a.w * scale * w.w * (1.f / (1.f + expf(-gv.w)));
    ((float4*)(o + t * 1024))[tid] = r;
}

// ---------------------------------------------------------------------------
extern "C" void kernel_launch(void* const* d_in, const int* in_sizes, int n_in,
                              void* d_out, int out_size, void* d_ws, size_t ws_size,
                              hipStream_t stream)
{
    const float* x    = (const float*)d_in[0];
    const float* qU   = (const float*)d_in[1];
    const float* qV   = (const float*)d_in[2];
    const float* kU   = (const float*)d_in[3];
    const float* kV   = (const float*)d_in[4];
    const float* vU   = (const float*)d_in[5];
    const float* vV   = (const float*)d_in[6];
    const float* ql   = (const float*)d_in[7];
    const float* kl   = (const float*)d_in[8];
    const float* vl   = (const float*)d_in[9];
    const float* gl   = (const float*)d_in[10];
    const float* dw   = (const float*)d_in[11];
    const float* db   = (const float*)d_in[12];
    const float* ogw  = (const float*)d_in[13];
    const float* opw  = (const float*)d_in[14];
    const float* rmsw = (const float*)d_in[15];

    // workspace layout (floats): total ~46.3M floats = ~177 MB
    float* W  = (float*)d_ws;
    int*   sel_idx = (int*)W;            // 16 ints
    float* sel_w   = W + 16;             // 16 floats
    float* dec     = W + 32;             // TOK*16 = 131072
    float* WEFF    = W + 32 + 131072;    // 4 * 1024*1024
    float* Q   = WEFF + 4 * 1048576;     // 4 x [TOK,1024]
    float* Kp  = Q   + NT_ELE;
    float* Vp  = Kp  + NT_ELE;
    float* G   = Vp  + NT_ELE;
    float* ATT = G   + NT_ELE;
    float* GPRE = Kp;   // reused after scan consumes K
    float* RMSO = Vp;   // reused after scan consumes V

    topk_kernel<<<1, 64, 0, stream>>>(ql, kl, vl, gl, sel_idx, sel_w);

    // W_eff per projection (q,k,v,gate) — gate uses v_U/v_V with gate weights
    weff_kernel<<<dim3(8, 8, 4), 256, 0, stream>>>(qU, kU, vU, qV, kV, vV,
                                                   WEFF, sel_idx, sel_w);

    // q,k,v,gate = x @ W_eff_p   (batched over z)
    gemm128<0><<<dim3(8, 64, 4), 256, 0, stream>>>(x, WEFF, Q,
                                                   (size_t)1048576, (size_t)NT_ELE);

    decay_kernel<<<(TOK * 16) / 256, 256, 0, stream>>>(x, dw, db, dec);

    scan_kernel<<<64, 64, 0, stream>>>(Q, Kp, Vp, G, dec, ATT);

    // out-gate pre-activation: g = x @ out_gate_w^T  (NT)
    gemm128<1><<<dim3(8, 64, 1), 256, 0, stream>>>(x, ogw, GPRE, 0, 0);

    rms_gate_kernel<<<TOK, 256, 0, stream>>>(ATT, GPRE, rmsw, RMSO);

    // final: out = rmso @ out_proj_w^T  (NT)
    gemm128<1><<<dim3(8, 64, 1), 256, 0, stream>>>(RMSO, opw, (float*)d_out, 0, 0);
}

// Round 2
// 553.742 us; speedup vs baseline: 3.8806x; 3.8806x over previous
//
#include <hip/hip_runtime.h>
#include <hip/hip_bf16.h>

// Problem constants (B=4, S=2048, D_MODEL=1024, H=16, DH=64, RANK=256, NPRIM=16, top_k=4)
#define TOK 8192
#define SEQ 2048
#define CT  64          // scan chunk length
#define NC  32          // chunks per sequence

typedef __attribute__((ext_vector_type(8))) short bf16x8;   // 8 bf16 = 4 VGPRs
typedef __attribute__((ext_vector_type(4))) float f32x4;
typedef unsigned short u16;
typedef unsigned int   u32;

__device__ __forceinline__ u16 f2bf(float f) {
    u32 u = __float_as_uint(f);
    u = (u + 0x7FFFu + ((u >> 16) & 1u)) >> 16;   // RNE
    return (u16)u;
}
__device__ __forceinline__ float b2f(u16 h) { return __uint_as_float(((u32)h) << 16); }
__device__ __forceinline__ float sigf(float z) { return 1.f / (1.f + __expf(-z)); }

// ---------------------------------------------------------------------------
// Top-4: softmax->top_k->renorm == softmax over the top-4 logits (exact)
// ---------------------------------------------------------------------------
__global__ void topk_kernel(const float* __restrict__ ql, const float* __restrict__ kl,
                            const float* __restrict__ vl, const float* __restrict__ gl,
                            int* __restrict__ sel_idx, float* __restrict__ sel_w)
{
    const int p = threadIdx.x;
    if (p >= 4) return;
    const float* lg = (p == 0) ? ql : (p == 1) ? kl : (p == 2) ? vl : gl;
    float v[16];
    for (int i = 0; i < 16; i++) v[i] = lg[i];
    bool used[16];
    for (int i = 0; i < 16; i++) used[i] = false;
    int idx[4]; float val[4];
    for (int k = 0; k < 4; k++) {
        int bi = -1; float bv = -__builtin_inff();
        for (int i = 0; i < 16; i++)
            if (!used[i] && v[i] > bv) { bv = v[i]; bi = i; }
        used[bi] = true; idx[k] = bi; val[k] = bv;
    }
    const float m = val[0];
    float e[4], s = 0.f;
    for (int k = 0; k < 4; k++) { e[k] = expf(val[k] - m); s += e[k]; }
    for (int k = 0; k < 4; k++) { sel_idx[p*4 + k] = idx[k]; sel_w[p*4 + k] = e[k] / s; }
}

// ---------------------------------------------------------------------------
// fp32 -> bf16 bulk convert (n4 = count of float4 groups)
// ---------------------------------------------------------------------------
__global__ __launch_bounds__(256)
void f2b_kernel(const float* __restrict__ in, u16* __restrict__ out, int n4)
{
    const int i = blockIdx.x * 256 + threadIdx.x;
    if (i >= n4) return;
    const float4 v = ((const float4*)in)[i];
    __align__(8) u16 t[4] = { f2bf(v.x), f2bf(v.y), f2bf(v.z), f2bf(v.w) };
    ((uint2*)out)[i] = *(const uint2*)t;
}

// ---------------------------------------------------------------------------
// W_eff builder (fp32 VALU): writes TRANSPOSED bf16 WT[p][o][d] so it is the
// [N][K] B-operand of the MFMA GEMM. W_eff[d][o] = sum_s w_s U_s[d,:]V_s[:,o].
// ---------------------------------------------------------------------------
__global__ __launch_bounds__(256)
void weff_kernel(const float* __restrict__ qU, const float* __restrict__ kU, const float* __restrict__ vU,
                 const float* __restrict__ qV, const float* __restrict__ kV, const float* __restrict__ vV,
                 u16* __restrict__ WT,
                 const int* __restrict__ sel_idx_all, const float* __restrict__ sel_w_all)
{
    const int p = blockIdx.z;
    const float* U = (p == 0) ? qU : (p == 1) ? kU : vU;
    const float* V = (p == 0) ? qV : (p == 1) ? kV : vV;
    const int*   si = sel_idx_all + p*4;
    const float* sw = sel_w_all  + p*4;
    u16* C = WT + (size_t)p * 1024 * 1024;

    __shared__ float As[8][132];
    __shared__ float Bs[8][132];
    const int tid = threadIdx.x;
    const int n0 = blockIdx.x * 128, m0 = blockIdx.y * 128;
    const int tx = tid & 15, ty = tid >> 4;
    const int ar = tid >> 1,  ac  = (tid & 1) << 2;
    const int bnr = tid >> 5, bnc = (tid & 31) << 2;

    int prim[4]; float wsel[4];
    #pragma unroll
    for (int i = 0; i < 4; i++) { prim[i] = si[i]; wsel[i] = sw[i]; }

    float acc[8][8]{};
    for (int k0 = 0; k0 < 1024; k0 += 8) {
        const int blk = k0 >> 8;
        const float* Ub = U + (size_t)prim[blk] * (1024 * 256);
        const float* Vb = V + (size_t)prim[blk] * (256 * 1024);
        const float wv = wsel[blk];
        float4 a4 = *(const float4*)(Ub + (size_t)(m0 + ar) * 256 + (k0 & 255) + ac);
        a4.x *= wv; a4.y *= wv; a4.z *= wv; a4.w *= wv;
        float4 b4 = *(const float4*)(Vb + (size_t)((k0 & 255) + bnr) * 1024 + n0 + bnc);
        __syncthreads();
        As[ac+0][ar] = a4.x; As[ac+1][ar] = a4.y; As[ac+2][ar] = a4.z; As[ac+3][ar] = a4.w;
        *(float4*)&Bs[bnr][bnc] = b4;
        __syncthreads();
        #pragma unroll
        for (int kk = 0; kk < 8; kk++) {
            float av[8], bv[8];
            *(float4*)&av[0] = *(const float4*)&As[kk][ty*8];
            *(float4*)&av[4] = *(const float4*)&As[kk][ty*8 + 4];
            *(float4*)&bv[0] = *(const float4*)&Bs[kk][tx*8];
            *(float4*)&bv[4] = *(const float4*)&Bs[kk][tx*8 + 4];
            #pragma unroll
            for (int i = 0; i < 8; i++)
                #pragma unroll
                for (int j = 0; j < 8; j++)
                    acc[i][j] = fmaf(av[i], bv[j], acc[i][j]);
        }
    }
    // transposed bf16 store: WT row = n (output dim o), col = m (model dim d)
    #pragma unroll
    for (int j = 0; j < 8; j++) {
        __align__(16) u16 tmp[8];
        #pragma unroll
        for (int i = 0; i < 8; i++) tmp[i] = f2bf(acc[i][j]);
        u16* cr = C + (size_t)(n0 + tx*8 + j) * 1024 + m0 + ty*8;
        *(uint4*)cr = *(const uint4*)tmp;
    }
}

// ---------------------------------------------------------------------------
// bf16 MFMA GEMM, M=8192 (grid.y*128), N=K=1024. A [M][1024] bf16 row-major,
// Bt [1024][1024] bf16 row-major [n][k] (i.e. B^T). C[m][n] += A[m][k]*Bt[n][k].
// 128x128x64 tile, 4 waves of 4x4 16x16x32 fragments, global_load_lds w=16,
// XOR-swizzled LDS chunks (chunk j of a row holds global chunk j^(row&7)) so
// fragment ds_read_b128s are 2-way (free) instead of 16-way conflicted.
// blockIdx.z strides Bt by bstride and C by cstride (elements).
// ---------------------------------------------------------------------------
template<int OUTBF>
__global__ __launch_bounds__(256)
void mfma_gemm(const u16* __restrict__ A, const u16* __restrict__ Bt,
               void* __restrict__ Cout, size_t bstride, size_t cstride)
{
    __shared__ u16 As[128 * 64];
    __shared__ u16 Bs[128 * 64];
    const u16* B = Bt + (size_t)blockIdx.z * bstride;
    const int tid  = threadIdx.x;
    const int lane = tid & 63, wave = tid >> 6;
    const int m0 = blockIdx.y * 128, n0 = blockIdx.x * 128;
    const int wm = (wave >> 1) * 64, wn = (wave & 1) * 64;

    f32x4 acc[4][4];
    #pragma unroll
    for (int i = 0; i < 4; i++)
        #pragma unroll
        for (int j = 0; j < 4; j++) acc[i][j] = (f32x4)0.f;

    for (int k0 = 0; k0 < 1024; k0 += 64) {
        __syncthreads();   // LDS from previous iter fully consumed
        #pragma unroll
        for (int it = 0; it < 4; it++) {
            const int c   = it * 256 + tid;
            const int row = c >> 3, j = c & 7;
            const int g   = j ^ (row & 7);
            const u16* ga = A + (size_t)(m0 + row) * 1024 + k0 + g * 8;
            __builtin_amdgcn_global_load_lds(
                (const __attribute__((address_space(1))) u32*)ga,
                (__attribute__((address_space(3))) u32*)&As[(it * 256 + wave * 64) * 8],
                16, 0, 0);
            const u16* gb = B + (size_t)(n0 + row) * 1024 + k0 + g * 8;
            __builtin_amdgcn_global_load_lds(
                (const __attribute__((address_space(1))) u32*)gb,
                (__attribute__((address_space(3))) u32*)&Bs[(it * 256 + wave * 64) * 8],
                16, 0, 0);
        }
        __syncthreads();   // drains vmcnt for global_load_lds
        #pragma unroll
        for (int ks = 0; ks < 2; ks++) {
            bf16x8 af[4], bfr[4];
            const int gk = ks * 4 + (lane >> 4);
            #pragma unroll
            for (int mi = 0; mi < 4; mi++) {
                const int r  = wm + mi * 16 + (lane & 15);
                const int ja = gk ^ (r & 7);
                af[mi] = *(const bf16x8*)&As[r * 64 + ja * 8];
                const int rn = wn + mi * 16 + (lane & 15);
                const int jb = gk ^ (rn & 7);
                bfr[mi] = *(const bf16x8*)&Bs[rn * 64 + jb * 8];
            }
            #pragma unroll
            for (int mi = 0; mi < 4; mi++)
                #pragma unroll
                for (int ni = 0; ni < 4; ni++)
                    acc[mi][ni] = __builtin_amdgcn_mfma_f32_16x16x32_bf16(
                        af[mi], bfr[ni], acc[mi][ni], 0, 0, 0);
        }
    }
    // epilogue: C/D layout col=lane&15, row=(lane>>4)*4+reg  [m89-verified]
    const int col_l = lane & 15, row_l = (lane >> 4) * 4;
    if (OUTBF) {
        u16* C = (u16*)Cout + (size_t)blockIdx.z * cstride;
        #pragma unroll
        for (int mi = 0; mi < 4; mi++)
            #pragma unroll
            for (int ni = 0; ni < 4; ni++)
                #pragma unroll
                for (int i = 0; i < 4; i++) {
                    const int r  = m0 + wm + mi * 16 + row_l + i;
                    const int cn = n0 + wn + ni * 16 + col_l;
                    C[(size_t)r * 1024 + cn] = f2bf(acc[mi][ni][i]);
                }
    } else {
        float* C = (float*)Cout + (size_t)blockIdx.z * cstride;
        #pragma unroll
        for (int mi = 0; mi < 4; mi++)
            #pragma unroll
            for (int ni = 0; ni < 4; ni++)
                #pragma unroll
                for (int i = 0; i < 4; i++) {
                    const int r  = m0 + wm + mi * 16 + row_l + i;
                    const int cn = n0 + wn + ni * 16 + col_l;
                    C[(size_t)r * 1024 + cn] = acc[mi][ni][i];
                }
    }
}

// ---------------------------------------------------------------------------
// Decay: one wave per token; x row in registers, 16 head dots, butterfly
// reduce. dec[t][h] = sigmoid(-(x.dw_h + b_h)) = 1/(1+exp(z)).
// ---------------------------------------------------------------------------
__global__ __launch_bounds__(256)
void decay_kernel(const float* __restrict__ x, const float* __restrict__ dw,
                  const float* __restrict__ db, float* __restrict__ dec)
{
    const int wave = threadIdx.x >> 6, lane = threadIdx.x & 63;
    const int t = blockIdx.x * 4 + wave;
    const float4* x4 = (const float4*)(x + (size_t)t * 1024);
    float4 xv[4];
    #pragma unroll
    for (int i = 0; i < 4; i++) xv[i] = x4[lane + 64 * i];
    float p[16];
    #pragma unroll
    for (int h = 0; h < 16; h++) {
        const float4* w4 = (const float4*)(dw + (size_t)h * 1024);
        float s = 0.f;
        #pragma unroll
        for (int i = 0; i < 4; i++) {
            const float4 wv = w4[lane + 64 * i];
            s = fmaf(xv[i].x, wv.x, fmaf(xv[i].y, wv.y,
                fmaf(xv[i].z, wv.z, fmaf(xv[i].w, wv.w, s))));
        }
        p[h] = s;
    }
    #pragma unroll
    for (int off = 32; off > 0; off >>= 1)
        #pragma unroll
        for (int h = 0; h < 16; h++) p[h] += __shfl_xor(p[h], off);
    if (lane == 0) {
        #pragma unroll
        for (int h = 0; h < 16; h++)
            dec[(size_t)t * 16 + h] = 1.f / (1.f + __expf(p[h] + db[h]));
    }
}

// ---------------------------------------------------------------------------
// Chunk-parallel scan, 3 phases. s_t = a_t*s_{t-1} + sigmoid(g)*k*v; out=q*s.
// ---------------------------------------------------------------------------
__global__ __launch_bounds__(64)
void scan1(const u16* __restrict__ Kq, const u16* __restrict__ Vq, const u16* __restrict__ Gq,
           const float* __restrict__ dec, float* __restrict__ Lc, float* __restrict__ Pc)
{
    const int c = blockIdx.x & 31, h = (blockIdx.x >> 5) & 15, b = blockIdx.x >> 9;
    const int d = threadIdx.x;
    const size_t t0 = (size_t)b * SEQ + c * CT;
    const size_t base = t0 * 1024 + h * 64 + d;
    const u16* kp = Kq + base;
    const u16* vp = Vq + base;
    const u16* gp = Gq + base;
    const float* dp = dec + t0 * 16 + h;
    float s = 0.f, P = 1.f;
    #pragma unroll 4
    for (int t = 0; t < CT; t++) {
        const size_t o = (size_t)t * 1024;
        const float a  = dp[t * 16];
        const float kv = b2f(kp[o]) * b2f(vp[o]) * sigf(b2f(gp[o]));
        s = fmaf(a, s, kv);
        P *= a;
    }
    const int ci = (b * 16 + h) * NC + c;
    Lc[(size_t)ci * 64 + d] = s;
    if (d == 0) Pc[ci] = P;
}

__global__ __launch_bounds__(64)
void scan2(const float* __restrict__ Lc, const float* __restrict__ Pc, float* __restrict__ Ic)
{
    const int bh = blockIdx.x, d = threadIdx.x;
    float S = 0.f;
    for (int c = 0; c < NC; c++) {
        const int ci = bh * NC + c;
        Ic[(size_t)ci * 64 + d] = S;
        S = fmaf(Pc[ci], S, Lc[(size_t)ci * 64 + d]);
    }
}

__global__ __launch_bounds__(64)
void scan3(const u16* __restrict__ Qq, const u16* __restrict__ Kq,
           const u16* __restrict__ Vq, const u16* __restrict__ Gq,
           const float* __restrict__ dec, const float* __restrict__ Ic,
           float* __restrict__ out)
{
    const int c = blockIdx.x & 31, h = (blockIdx.x >> 5) & 15, b = blockIdx.x >> 9;
    const int d = threadIdx.x;
    const size_t t0 = (size_t)b * SEQ + c * CT;
    const size_t base = t0 * 1024 + h * 64 + d;
    const u16* qp = Qq + base;
    const u16* kp = Kq + base;
    const u16* vp = Vq + base;
    const u16* gp = Gq + base;
    const float* dp = dec + t0 * 16 + h;
    const int ci = (b * 16 + h) * NC + c;
    float s = Ic[(size_t)ci * 64 + d];
    #pragma unroll 4
    for (int t = 0; t < CT; t++) {
        const size_t o = (size_t)t * 1024;
        const float a  = dp[t * 16];
        const float kv = b2f(kp[o]) * b2f(vp[o]) * sigf(b2f(gp[o]));
        s = fmaf(a, s, kv);
        out[base + o] = b2f(qp[o]) * s;
    }
}

// ---------------------------------------------------------------------------
// RMSNorm * rms_w * sigmoid(gpre) -> bf16, one block per token
// ---------------------------------------------------------------------------
__global__ __launch_bounds__(256)
void rms_gate(const float* __restrict__ att, const u16* __restrict__ gpre,
              const float* __restrict__ rmsw, u16* __restrict__ o)
{
    const size_t t = blockIdx.x;
    const int tid = threadIdx.x;
    const float4 a = ((const float4*)(att + t * 1024))[tid];
    float ss = a.x*a.x + a.y*a.y + a.z*a.z + a.w*a.w;
    #pragma unroll
    for (int d = 32; d > 0; d >>= 1) ss += __shfl_down(ss, d);
    __shared__ float red[4];
    if ((tid & 63) == 0) red[tid >> 6] = ss;
    __syncthreads();
    const float tot = red[0] + red[1] + red[2] + red[3];
    const float scale = rsqrtf(tot * (1.0f / 1024.0f) + 1.1920929e-7f);
    const ushort4 g4 = ((const ushort4*)(gpre + t * 1024))[tid];
    const float4 w   = ((const float4*)rmsw)[tid];
    __align__(8) u16 r[4];
    r[0] = f2bf(a.x * scale * w.x * sigf(b2f(g4.x)));
    r[1] = f2bf(a.y * scale * w.y * sigf(b2f(g4.y)));
    r[2] = f2bf(a.z * scale * w.z * sigf(b2f(g4.z)));
    r[3] = f2bf(a.w * scale * w.w * sigf(b2f(g4.w)));
    ((uint2*)(o + t * 1024))[tid] = *(const uint2*)r;
}

// ---------------------------------------------------------------------------
extern "C" void kernel_launch(void* const* d_in, const int* in_sizes, int n_in,
                              void* d_out, int out_size, void* d_ws, size_t ws_size,
                              hipStream_t stream)
{
    const float* x    = (const float*)d_in[0];
    const float* qU   = (const float*)d_in[1];
    const float* qV   = (const float*)d_in[2];
    const float* kU   = (const float*)d_in[3];
    const float* kV   = (const float*)d_in[4];
    const float* vU   = (const float*)d_in[5];
    const float* vV   = (const float*)d_in[6];
    const float* ql   = (const float*)d_in[7];
    const float* kl   = (const float*)d_in[8];
    const float* vl   = (const float*)d_in[9];
    const float* gl   = (const float*)d_in[10];
    const float* dw   = (const float*)d_in[11];
    const float* db   = (const float*)d_in[12];
    const float* ogw  = (const float*)d_in[13];
    const float* opw  = (const float*)d_in[14];
    const float* rmsw = (const float*)d_in[15];

    // workspace layout (byte offsets, ~157.5 MB total)
    char* w = (char*)d_ws;
    int*   sel_idx = (int*)  (w + 0);            // 64 B
    float* sel_w   = (float*)(w + 64);           // 64 B
    float* dec     = (float*)(w + 128);          // 8192*16*4 = 512 KB
    u16*   WT      = (u16*)  (w + 524544);       // 4*1M bf16 = 8 MB
    u16*   xb      = (u16*)  (w + 8913152);      // 8192*1024 bf16 = 16 MB
    u16*   ogwb    = (u16*)  (w + 25690368);     // 1M bf16 = 2 MB
    u16*   opwb    = (u16*)  (w + 27787520);     // 2 MB
    u16*   QKVG    = (u16*)  (w + 29884672);     // 4 * 8192*1024 bf16 = 64 MB
    u16*   GPRE    = (u16*)  (w + 96993536);     // 16 MB
    u16*   RMSO    = (u16*)  (w + 113770752);    // 16 MB
    float* ATT     = (float*)(w + 130547968);    // 32 MB
    float* Lc      = (float*)(w + 164102400);    // 64*32*64*4 = 512 KB
    float* Ic      = (float*)(w + 164626688);    // 512 KB
    float* Pc      = (float*)(w + 165150976);    // 8 KB

    topk_kernel<<<1, 64, 0, stream>>>(ql, kl, vl, gl, sel_idx, sel_w);

    f2b_kernel<<<8192, 256, 0, stream>>>(x,   xb,   2097152);
    f2b_kernel<<<1024, 256, 0, stream>>>(ogw, ogwb, 262144);
    f2b_kernel<<<1024, 256, 0, stream>>>(opw, opwb, 262144);

    weff_kernel<<<dim3(8, 8, 4), 256, 0, stream>>>(qU, kU, vU, qV, kV, vV,
                                                   WT, sel_idx, sel_w);

    // q,k,v,gate = x @ W_eff_p  -> bf16, batched over z
    mfma_gemm<1><<<dim3(8, 64, 4), 256, 0, stream>>>(xb, WT, QKVG,
                                                     (size_t)1048576, (size_t)8388608);

    decay_kernel<<<2048, 256, 0, stream>>>(x, dw, db, dec);

    // chunk-parallel scan
    scan1<<<2048, 64, 0, stream>>>(QKVG + 8388608, QKVG + 16777216, QKVG + 25165824,
                                   dec, Lc, Pc);
    scan2<<<64, 64, 0, stream>>>(Lc, Pc, Ic);
    scan3<<<2048, 64, 0, stream>>>(QKVG, QKVG + 8388608, QKVG + 16777216, QKVG + 25165824,
                                   dec, Ic, ATT);

    // out-gate pre-activation: x @ out_gate_w^T -> bf16
    mfma_gemm<1><<<dim3(8, 64, 1), 256, 0, stream>>>(xb, ogwb, GPRE, 0, 0);

    rms_gate<<<8192, 256, 0, stream>>>(ATT, GPRE, rmsw, RMSO);

    // final: rmso @ out_proj_w^T -> fp32 d_out
    mfma_gemm<0><<<dim3(8, 64, 1), 256, 0, stream>>>(RMSO, opwb, (float*)d_out, 0, 0);
}

// Round 3
// 414.425 us; speedup vs baseline: 5.1852x; 1.3362x over previous
//
#include <hip/hip_runtime.h>
#include <hip/hip_bf16.h>

// Problem constants (B=4, S=2048, D_MODEL=1024, H=16, DH=64, RANK=256, NPRIM=16, top_k=4)
#define TOK 8192
#define SEQ 2048
#define CT  64          // scan chunk length
#define NC  32          // chunks per sequence

typedef __attribute__((ext_vector_type(8))) short bf16x8;   // 8 bf16 = 4 VGPRs
typedef __attribute__((ext_vector_type(4))) float f32x4;
typedef unsigned short u16;
typedef unsigned int   u32;

__device__ __forceinline__ u16 f2bf(float f) {
    u32 u = __float_as_uint(f);
    u = (u + 0x7FFFu + ((u >> 16) & 1u)) >> 16;   // RNE
    return (u16)u;
}
__device__ __forceinline__ float b2f(u16 h) { return __uint_as_float(((u32)h) << 16); }
__device__ __forceinline__ float sigf(float z) { return 1.f / (1.f + __expf(-z)); }

// ---------------------------------------------------------------------------
// Top-4: softmax->top_k->renorm == softmax over the top-4 logits (exact)
// ---------------------------------------------------------------------------
__global__ void topk_kernel(const float* __restrict__ ql, const float* __restrict__ kl,
                            const float* __restrict__ vl, const float* __restrict__ gl,
                            int* __restrict__ sel_idx, float* __restrict__ sel_w)
{
    const int p = threadIdx.x;
    if (p >= 4) return;
    const float* lg = (p == 0) ? ql : (p == 1) ? kl : (p == 2) ? vl : gl;
    float v[16];
    for (int i = 0; i < 16; i++) v[i] = lg[i];
    bool used[16];
    for (int i = 0; i < 16; i++) used[i] = false;
    int idx[4]; float val[4];
    for (int k = 0; k < 4; k++) {
        int bi = -1; float bv = -__builtin_inff();
        for (int i = 0; i < 16; i++)
            if (!used[i] && v[i] > bv) { bv = v[i]; bi = i; }
        used[bi] = true; idx[k] = bi; val[k] = bv;
    }
    const float m = val[0];
    float e[4], s = 0.f;
    for (int k = 0; k < 4; k++) { e[k] = expf(val[k] - m); s += e[k]; }
    for (int k = 0; k < 4; k++) { sel_idx[p*4 + k] = idx[k]; sel_w[p*4 + k] = e[k] / s; }
}

// ---------------------------------------------------------------------------
// fp32 -> bf16 bulk convert (n4 = count of float4 groups)
// ---------------------------------------------------------------------------
__global__ __launch_bounds__(256)
void f2b_kernel(const float* __restrict__ in, u16* __restrict__ out, int n4)
{
    const int i = blockIdx.x * 256 + threadIdx.x;
    if (i >= n4) return;
    const float4 v = ((const float4*)in)[i];
    __align__(8) u16 t[4] = { f2bf(v.x), f2bf(v.y), f2bf(v.z), f2bf(v.w) };
    ((uint2*)out)[i] = *(const uint2*)t;
}

// ---------------------------------------------------------------------------
// gatherU: gU[p][d][k=s*256+r] = w_s * U_sel[p][s][d][r]  -> bf16, coalesced
// ---------------------------------------------------------------------------
__global__ __launch_bounds__(256)
void gatherU(const float* __restrict__ qU, const float* __restrict__ kU,
             const float* __restrict__ vU, u16* __restrict__ gU,
             const int* __restrict__ sel_idx_all, const float* __restrict__ sel_w_all)
{
    const int p = blockIdx.z;
    const float* U = (p == 0) ? qU : (p == 1) ? kU : vU;
    const int g = blockIdx.x * 256 + threadIdx.x;   // float4-group over [d][k/4]
    const int d = g >> 8, kq = g & 255;
    const int k = kq << 2;
    const int s = k >> 8, r = k & 255;
    const int prim = sel_idx_all[p * 4 + s];
    const float wv = sel_w_all[p * 4 + s];
    const float4 v = *(const float4*)(U + (size_t)prim * (1024 * 256) + (size_t)d * 256 + r);
    __align__(8) u16 t[4] = { f2bf(v.x * wv), f2bf(v.y * wv), f2bf(v.z * wv), f2bf(v.w * wv) };
    ((uint2*)(gU + (size_t)p * 1048576))[g] = *(const uint2*)t;
}

// ---------------------------------------------------------------------------
// gatherVT: gVT[p][o][k=s*256+r] = V_sel[p][s][r][o]  -> bf16, LDS transpose
// ---------------------------------------------------------------------------
__global__ __launch_bounds__(256)
void gatherVT(const float* __restrict__ qV, const float* __restrict__ kV,
              const float* __restrict__ vV, u16* __restrict__ gVT,
              const int* __restrict__ sel_idx_all)
{
    const int p = blockIdx.z;
    const float* V = (p == 0) ? qV : (p == 1) ? kV : vV;
    const int o0 = blockIdx.x * 64;
    const int k0 = blockIdx.y * 64;
    const int s = k0 >> 8, r0 = k0 & 255;
    const int prim = sel_idx_all[p * 4 + s];
    const float* Vb = V + (size_t)prim * (256 * 1024);

    __shared__ float tile[64][68];
    const int tid = threadIdx.x;
    const int rr = tid >> 4, cc = (tid & 15) << 2;
    #pragma unroll
    for (int i = 0; i < 4; i++) {
        const float4 v = *(const float4*)(Vb + (size_t)(r0 + rr + 16 * i) * 1024 + o0 + cc);
        *(float4*)&tile[rr + 16 * i][cc] = v;
    }
    __syncthreads();
    const int oo = tid >> 4, kk = (tid & 15) << 2;
    u16* out = gVT + (size_t)p * 1048576;
    #pragma unroll
    for (int i = 0; i < 4; i++) {
        __align__(8) u16 t[4];
        #pragma unroll
        for (int j = 0; j < 4; j++) t[j] = f2bf(tile[kk + j][oo + 16 * i]);
        *(uint2*)(out + (size_t)(o0 + oo + 16 * i) * 1024 + k0 + kk) = *(const uint2*)t;
    }
}

// ---------------------------------------------------------------------------
// bf16 MFMA GEMM, M = grid.y*128, N=K=1024. A [M][1024] bf16 row-major,
// Bt [1024][1024] bf16 row-major [n][k] (i.e. B^T). C[m][n] = sum A[m,k]*Bt[n,k].
// 128x128x64 tile, 4 waves of 4x4 16x16x32 fragments, global_load_lds w=16,
// XOR-swizzled LDS. blockIdx.z strides A/Bt/C by astride/bstride/cstride.
// ---------------------------------------------------------------------------
template<int OUTBF>
__global__ __launch_bounds__(256)
void mfma_gemm(const u16* __restrict__ Asrc, const u16* __restrict__ Bt,
               void* __restrict__ Cout, size_t astride, size_t bstride, size_t cstride)
{
    __shared__ u16 As[128 * 64];
    __shared__ u16 Bs[128 * 64];
    const u16* A = Asrc + (size_t)blockIdx.z * astride;
    const u16* B = Bt + (size_t)blockIdx.z * bstride;
    const int tid  = threadIdx.x;
    const int lane = tid & 63, wave = tid >> 6;
    const int m0 = blockIdx.y * 128, n0 = blockIdx.x * 128;
    const int wm = (wave >> 1) * 64, wn = (wave & 1) * 64;

    f32x4 acc[4][4];
    #pragma unroll
    for (int i = 0; i < 4; i++)
        #pragma unroll
        for (int j = 0; j < 4; j++) acc[i][j] = (f32x4)0.f;

    for (int k0 = 0; k0 < 1024; k0 += 64) {
        __syncthreads();
        #pragma unroll
        for (int it = 0; it < 4; it++) {
            const int c   = it * 256 + tid;
            const int row = c >> 3, j = c & 7;
            const int g   = j ^ (row & 7);
            const u16* ga = A + (size_t)(m0 + row) * 1024 + k0 + g * 8;
            __builtin_amdgcn_global_load_lds(
                (const __attribute__((address_space(1))) u32*)ga,
                (__attribute__((address_space(3))) u32*)&As[(it * 256 + wave * 64) * 8],
                16, 0, 0);
            const u16* gb = B + (size_t)(n0 + row) * 1024 + k0 + g * 8;
            __builtin_amdgcn_global_load_lds(
                (const __attribute__((address_space(1))) u32*)gb,
                (__attribute__((address_space(3))) u32*)&Bs[(it * 256 + wave * 64) * 8],
                16, 0, 0);
        }
        __syncthreads();
        #pragma unroll
        for (int ks = 0; ks < 2; ks++) {
            bf16x8 af[4], bfr[4];
            const int gk = ks * 4 + (lane >> 4);
            #pragma unroll
            for (int mi = 0; mi < 4; mi++) {
                const int r  = wm + mi * 16 + (lane & 15);
                const int ja = gk ^ (r & 7);
                af[mi] = *(const bf16x8*)&As[r * 64 + ja * 8];
                const int rn = wn + mi * 16 + (lane & 15);
                const int jb = gk ^ (rn & 7);
                bfr[mi] = *(const bf16x8*)&Bs[rn * 64 + jb * 8];
            }
            #pragma unroll
            for (int mi = 0; mi < 4; mi++)
                #pragma unroll
                for (int ni = 0; ni < 4; ni++)
                    acc[mi][ni] = __builtin_amdgcn_mfma_f32_16x16x32_bf16(
                        af[mi], bfr[ni], acc[mi][ni], 0, 0, 0);
        }
    }
    // epilogue: C/D layout col=lane&15, row=(lane>>4)*4+reg  [m89-verified]
    const int col_l = lane & 15, row_l = (lane >> 4) * 4;
    if (OUTBF) {
        u16* C = (u16*)Cout + (size_t)blockIdx.z * cstride;
        #pragma unroll
        for (int mi = 0; mi < 4; mi++)
            #pragma unroll
            for (int ni = 0; ni < 4; ni++)
                #pragma unroll
                for (int i = 0; i < 4; i++) {
                    const int r  = m0 + wm + mi * 16 + row_l + i;
                    const int cn = n0 + wn + ni * 16 + col_l;
                    C[(size_t)r * 1024 + cn] = f2bf(acc[mi][ni][i]);
                }
    } else {
        float* C = (float*)Cout + (size_t)blockIdx.z * cstride;
        #pragma unroll
        for (int mi = 0; mi < 4; mi++)
            #pragma unroll
            for (int ni = 0; ni < 4; ni++)
                #pragma unroll
                for (int i = 0; i < 4; i++) {
                    const int r  = m0 + wm + mi * 16 + row_l + i;
                    const int cn = n0 + wn + ni * 16 + col_l;
                    C[(size_t)r * 1024 + cn] = acc[mi][ni][i];
                }
    }
}

// ---------------------------------------------------------------------------
// Decay: one wave per token; x row in registers, 16 head dots, butterfly
// reduce. dec[t][h] = sigmoid(-(x.dw_h + b_h)) = 1/(1+exp(z)).
// ---------------------------------------------------------------------------
__global__ __launch_bounds__(256)
void decay_kernel(const float* __restrict__ x, const float* __restrict__ dw,
                  const float* __restrict__ db, float* __restrict__ dec)
{
    const int wave = threadIdx.x >> 6, lane = threadIdx.x & 63;
    const int t = blockIdx.x * 4 + wave;
    const float4* x4 = (const float4*)(x + (size_t)t * 1024);
    float4 xv[4];
    #pragma unroll
    for (int i = 0; i < 4; i++) xv[i] = x4[lane + 64 * i];
    float p[16];
    #pragma unroll
    for (int h = 0; h < 16; h++) {
        const float4* w4 = (const float4*)(dw + (size_t)h * 1024);
        float s = 0.f;
        #pragma unroll
        for (int i = 0; i < 4; i++) {
            const float4 wv = w4[lane + 64 * i];
            s = fmaf(xv[i].x, wv.x, fmaf(xv[i].y, wv.y,
                fmaf(xv[i].z, wv.z, fmaf(xv[i].w, wv.w, s))));
        }
        p[h] = s;
    }
    #pragma unroll
    for (int off = 32; off > 0; off >>= 1)
        #pragma unroll
        for (int h = 0; h < 16; h++) p[h] += __shfl_xor(p[h], off);
    if (lane == 0) {
        #pragma unroll
        for (int h = 0; h < 16; h++)
            dec[(size_t)t * 16 + h] = 1.f / (1.f + __expf(p[h] + db[h]));
    }
}

// ---------------------------------------------------------------------------
// Chunk-parallel scan, 3 phases. s_t = a_t*s_{t-1} + sigmoid(g)*k*v; out=q*s.
// ---------------------------------------------------------------------------
__global__ __launch_bounds__(64)
void scan1(const u16* __restrict__ Kq, const u16* __restrict__ Vq, const u16* __restrict__ Gq,
           const float* __restrict__ dec, float* __restrict__ Lc, float* __restrict__ Pc)
{
    const int c = blockIdx.x & 31, h = (blockIdx.x >> 5) & 15, b = blockIdx.x >> 9;
    const int d = threadIdx.x;
    const size_t t0 = (size_t)b * SEQ + c * CT;
    const size_t base = t0 * 1024 + h * 64 + d;
    const u16* kp = Kq + base;
    const u16* vp = Vq + base;
    const u16* gp = Gq + base;
    const float* dp = dec + t0 * 16 + h;
    float s = 0.f, P = 1.f;
    #pragma unroll 4
    for (int t = 0; t < CT; t++) {
        const size_t o = (size_t)t * 1024;
        const float a  = dp[t * 16];
        const float kv = b2f(kp[o]) * b2f(vp[o]) * sigf(b2f(gp[o]));
        s = fmaf(a, s, kv);
        P *= a;
    }
    const int ci = (b * 16 + h) * NC + c;
    Lc[(size_t)ci * 64 + d] = s;
    if (d == 0) Pc[ci] = P;
}

__global__ __launch_bounds__(64)
void scan2(const float* __restrict__ Lc, const float* __restrict__ Pc, float* __restrict__ Ic)
{
    const int bh = blockIdx.x, d = threadIdx.x;
    float S = 0.f;
    for (int c = 0; c < NC; c++) {
        const int ci = bh * NC + c;
        Ic[(size_t)ci * 64 + d] = S;
        S = fmaf(Pc[ci], S, Lc[(size_t)ci * 64 + d]);
    }
}

__global__ __launch_bounds__(64)
void scan3(const u16* __restrict__ Qq, const u16* __restrict__ Kq,
           const u16* __restrict__ Vq, const u16* __restrict__ Gq,
           const float* __restrict__ dec, const float* __restrict__ Ic,
           float* __restrict__ out)
{
    const int c = blockIdx.x & 31, h = (blockIdx.x >> 5) & 15, b = blockIdx.x >> 9;
    const int d = threadIdx.x;
    const size_t t0 = (size_t)b * SEQ + c * CT;
    const size_t base = t0 * 1024 + h * 64 + d;
    const u16* qp = Qq + base;
    const u16* kp = Kq + base;
    const u16* vp = Vq + base;
    const u16* gp = Gq + base;
    const float* dp = dec + t0 * 16 + h;
    const int ci = (b * 16 + h) * NC + c;
    float s = Ic[(size_t)ci * 64 + d];
    #pragma unroll 4
    for (int t = 0; t < CT; t++) {
        const size_t o = (size_t)t * 1024;
        const float a  = dp[t * 16];
        const float kv = b2f(kp[o]) * b2f(vp[o]) * sigf(b2f(gp[o]));
        s = fmaf(a, s, kv);
        out[base + o] = b2f(qp[o]) * s;
    }
}

// ---------------------------------------------------------------------------
// RMSNorm * rms_w * sigmoid(gpre) -> bf16, one block per token
// ---------------------------------------------------------------------------
__global__ __launch_bounds__(256)
void rms_gate(const float* __restrict__ att, const u16* __restrict__ gpre,
              const float* __restrict__ rmsw, u16* __restrict__ o)
{
    const size_t t = blockIdx.x;
    const int tid = threadIdx.x;
    const float4 a = ((const float4*)(att + t * 1024))[tid];
    float ss = a.x*a.x + a.y*a.y + a.z*a.z + a.w*a.w;
    #pragma unroll
    for (int d = 32; d > 0; d >>= 1) ss += __shfl_down(ss, d);
    __shared__ float red[4];
    if ((tid & 63) == 0) red[tid >> 6] = ss;
    __syncthreads();
    const float tot = red[0] + red[1] + red[2] + red[3];
    const float scale = rsqrtf(tot * (1.0f / 1024.0f) + 1.1920929e-7f);
    const ushort4 g4 = ((const ushort4*)(gpre + t * 1024))[tid];
    const float4 w   = ((const float4*)rmsw)[tid];
    __align__(8) u16 r[4];
    r[0] = f2bf(a.x * scale * w.x * sigf(b2f(g4.x)));
    r[1] = f2bf(a.y * scale * w.y * sigf(b2f(g4.y)));
    r[2] = f2bf(a.z * scale * w.z * sigf(b2f(g4.z)));
    r[3] = f2bf(a.w * scale * w.w * sigf(b2f(g4.w)));
    ((uint2*)(o + t * 1024))[tid] = *(const uint2*)r;
}

// ---------------------------------------------------------------------------
extern "C" void kernel_launch(void* const* d_in, const int* in_sizes, int n_in,
                              void* d_out, int out_size, void* d_ws, size_t ws_size,
                              hipStream_t stream)
{
    const float* x    = (const float*)d_in[0];
    const float* qU   = (const float*)d_in[1];
    const float* qV   = (const float*)d_in[2];
    const float* kU   = (const float*)d_in[3];
    const float* kV   = (const float*)d_in[4];
    const float* vU   = (const float*)d_in[5];
    const float* vV   = (const float*)d_in[6];
    const float* ql   = (const float*)d_in[7];
    const float* kl   = (const float*)d_in[8];
    const float* vl   = (const float*)d_in[9];
    const float* gl   = (const float*)d_in[10];
    const float* dw   = (const float*)d_in[11];
    const float* db   = (const float*)d_in[12];
    const float* ogw  = (const float*)d_in[13];
    const float* opw  = (const float*)d_in[14];
    const float* rmsw = (const float*)d_in[15];

    // workspace layout (byte offsets, ~165.2 MB total)
    char* w = (char*)d_ws;
    int*   sel_idx = (int*)  (w + 0);            // 64 B
    float* sel_w   = (float*)(w + 64);           // 64 B
    float* dec     = (float*)(w + 128);          // 512 KB
    u16*   WT      = (u16*)  (w + 524544);       // 4*1M bf16 = 8 MB
    u16*   xb      = (u16*)  (w + 8913152);      // 16 MB
    u16*   ogwb    = (u16*)  (w + 25690368);     // 2 MB
    u16*   opwb    = (u16*)  (w + 27787520);     // 2 MB
    u16*   QKVG    = (u16*)  (w + 29884672);     // 64 MB
    u16*   GPRE    = (u16*)  (w + 96993536);     // 16 MB
    u16*   RMSO    = (u16*)  (w + 113770752);    // 16 MB
    float* ATT     = (float*)(w + 130547968);    // 32 MB
    float* Lc      = (float*)(w + 164102400);    // 512 KB
    float* Ic      = (float*)(w + 164626688);    // 512 KB
    float* Pc      = (float*)(w + 165150976);    // 8 KB
    // gU/gVT live in the QKVG region (consumed by weff-gemm before QKVG is written)
    u16*   gU      = QKVG;                       // 8 MB
    u16*   gVT     = QKVG + 4 * 1048576;         // 8 MB

    topk_kernel<<<1, 64, 0, stream>>>(ql, kl, vl, gl, sel_idx, sel_w);

    f2b_kernel<<<8192, 256, 0, stream>>>(x,   xb,   2097152);
    f2b_kernel<<<1024, 256, 0, stream>>>(ogw, ogwb, 262144);
    f2b_kernel<<<1024, 256, 0, stream>>>(opw, opwb, 262144);

    // gather selected prims to bf16 (w folded into U), V transposed
    gatherU <<<dim3(1024, 1, 4), 256, 0, stream>>>(qU, kU, vU, gU, sel_idx, sel_w);
    gatherVT<<<dim3(16, 16, 4),  256, 0, stream>>>(qV, kV, vV, gVT, sel_idx);

    // WT[p][o][d] = sum_k gVT[p][o,k] * gU[p][d,k]  (= W_eff^T, bf16 out)
    mfma_gemm<1><<<dim3(8, 8, 4), 256, 0, stream>>>(gVT, gU, WT,
                                                    (size_t)1048576, (size_t)1048576,
                                                    (size_t)1048576);

    // q,k,v,gate = x @ W_eff_p  -> bf16, batched over z
    mfma_gemm<1><<<dim3(8, 64, 4), 256, 0, stream>>>(xb, WT, QKVG,
                                                     (size_t)0, (size_t)1048576,
                                                     (size_t)8388608);

    decay_kernel<<<2048, 256, 0, stream>>>(x, dw, db, dec);

    // chunk-parallel scan
    scan1<<<2048, 64, 0, stream>>>(QKVG + 8388608, QKVG + 16777216, QKVG + 25165824,
                                   dec, Lc, Pc);
    scan2<<<64, 64, 0, stream>>>(Lc, Pc, Ic);
    scan3<<<2048, 64, 0, stream>>>(QKVG, QKVG + 8388608, QKVG + 16777216, QKVG + 25165824,
                                   dec, Ic, ATT);

    // out-gate pre-activation: x @ out_gate_w^T -> bf16
    mfma_gemm<1><<<dim3(8, 64, 1), 256, 0, stream>>>(xb, ogwb, GPRE, 0, 0, 0);

    rms_gate<<<8192, 256, 0, stream>>>(ATT, GPRE, rmsw, RMSO);

    // final: rmso @ out_proj_w^T -> fp32 d_out
    mfma_gemm<0><<<dim3(8, 64, 1), 256, 0, stream>>>(RMSO, opwb, (float*)d_out, 0, 0, 0);
}

// Round 4
// 411.717 us; speedup vs baseline: 5.2193x; 1.0066x over previous
//
#include <hip/hip_runtime.h>
#include <hip/hip_bf16.h>

// Problem constants (B=4, S=2048, D_MODEL=1024, H=16, DH=64, RANK=256, NPRIM=16, top_k=4)
#define TOK 8192
#define SEQ 2048
#define CT  64          // scan chunk length
#define NC  32          // chunks per sequence

typedef __attribute__((ext_vector_type(8))) short bf16x8;   // 8 bf16 = 4 VGPRs
typedef __attribute__((ext_vector_type(4))) float f32x4;
typedef unsigned short u16;
typedef unsigned int   u32;

__device__ __forceinline__ u16 f2bf(float f) {
    u32 u = __float_as_uint(f);
    u = (u + 0x7FFFu + ((u >> 16) & 1u)) >> 16;   // RNE
    return (u16)u;
}
__device__ __forceinline__ float b2f(u16 h) { return __uint_as_float(((u32)h) << 16); }
__device__ __forceinline__ float sigf(float z) { return 1.f / (1.f + __expf(-z)); }

// Top-4 of 16 logits + softmax over the kept 4 (== softmax->topk->renorm, exact).
__device__ __forceinline__ void topk4(const float* __restrict__ lg, int* idx, float* wv)
{
    float v[16];
    #pragma unroll
    for (int i = 0; i < 16; i++) v[i] = lg[i];
    bool used[16];
    #pragma unroll
    for (int i = 0; i < 16; i++) used[i] = false;
    float val[4];
    #pragma unroll
    for (int k = 0; k < 4; k++) {
        int bi = 0; float bv = -3.0e38f;
        #pragma unroll
        for (int i = 0; i < 16; i++)
            if (!used[i] && v[i] > bv) { bv = v[i]; bi = i; }
        used[bi] = true; idx[k] = bi; val[k] = bv;
    }
    float e[4], s = 0.f;
    #pragma unroll
    for (int k = 0; k < 4; k++) { e[k] = expf(val[k] - val[0]); s += e[k]; }
    #pragma unroll
    for (int k = 0; k < 4; k++) wv[k] = e[k] / s;
}

// ---------------------------------------------------------------------------
// fp32 -> bf16 bulk convert for x, out_gate_w, out_proj_w in one dispatch.
// 2621440 float4-groups total: [0,2097152) x, [.., 2359296) ogw, rest opw.
// ---------------------------------------------------------------------------
__global__ __launch_bounds__(256)
void f2b_all(const float* __restrict__ x, const float* __restrict__ ogw,
             const float* __restrict__ opw,
             u16* __restrict__ xb, u16* __restrict__ ogwb, u16* __restrict__ opwb)
{
    const int i = blockIdx.x * 256 + threadIdx.x;
    const float* src; u16* dst; int off;
    if (i < 2097152)      { src = x;   dst = xb;   off = i; }
    else if (i < 2359296) { src = ogw; dst = ogwb; off = i - 2097152; }
    else                  { src = opw; dst = opwb; off = i - 2359296; }
    const float4 v = ((const float4*)src)[off];
    __align__(8) u16 t[4] = { f2bf(v.x), f2bf(v.y), f2bf(v.z), f2bf(v.w) };
    ((uint2*)dst)[off] = *(const uint2*)t;
}

// ---------------------------------------------------------------------------
// gather_all: z<4 -> gVT[p][o][k]=V_sel (LDS transpose); z>=4 -> gU[p][d][k]=
// w_s*U_sel (straight copy). topk computed inline per thread (cheap, exact).
// grid (16,16,8), 64x64 tiles.
// ---------------------------------------------------------------------------
__global__ __launch_bounds__(256)
void gather_all(const float* __restrict__ qU, const float* __restrict__ kU,
                const float* __restrict__ vU,
                const float* __restrict__ qV, const float* __restrict__ kV,
                const float* __restrict__ vV,
                const float* __restrict__ ql, const float* __restrict__ kl,
                const float* __restrict__ vl, const float* __restrict__ gl,
                u16* __restrict__ gU, u16* __restrict__ gVT)
{
    const int z = blockIdx.z;
    const int p = z & 3;
    const float* lg = (p == 0) ? ql : (p == 1) ? kl : (p == 2) ? vl : gl;
    int idx[4]; float wsel[4];
    topk4(lg, idx, wsel);
    const int tid = threadIdx.x;

    if (z < 4) {
        // V^T gather: gVT[p][o][k=s*256+r] = V_sel[s][r][o]
        const float* V = (p == 0) ? qV : (p == 1) ? kV : vV;
        const int o0 = blockIdx.x * 64, k0 = blockIdx.y * 64;
        const int s = k0 >> 8, r0 = k0 & 255;
        const float* Vb = V + (size_t)idx[s] * (256 * 1024);
        __shared__ float tile[64][68];
        const int rr = tid >> 4, cc = (tid & 15) << 2;
        #pragma unroll
        for (int i = 0; i < 4; i++) {
            const float4 v = *(const float4*)(Vb + (size_t)(r0 + rr + 16 * i) * 1024 + o0 + cc);
            *(float4*)&tile[rr + 16 * i][cc] = v;
        }
        __syncthreads();
        const int oo = tid >> 4, kk = (tid & 15) << 2;
        u16* out = gVT + (size_t)p * 1048576;
        #pragma unroll
        for (int i = 0; i < 4; i++) {
            __align__(8) u16 t[4];
            #pragma unroll
            for (int j = 0; j < 4; j++) t[j] = f2bf(tile[kk + j][oo + 16 * i]);
            *(uint2*)(out + (size_t)(o0 + oo + 16 * i) * 1024 + k0 + kk) = *(const uint2*)t;
        }
    } else {
        // U gather: gU[p][d][k=s*256+r] = w_s * U_sel[s][d][r]
        const float* U = (p == 0) ? qU : (p == 1) ? kU : vU;
        const int d0 = blockIdx.x * 64, k0 = blockIdx.y * 64;
        const int s = k0 >> 8, r0 = k0 & 255;
        const float* Ub = U + (size_t)idx[s] * (1024 * 256);
        const float wq = wsel[s];
        u16* out = gU + (size_t)p * 1048576;
        const int rr = tid >> 4, cc = (tid & 15) << 2;
        #pragma unroll
        for (int i = 0; i < 4; i++) {
            const float4 v = *(const float4*)(Ub + (size_t)(d0 + rr + 16 * i) * 256 + r0 + cc);
            __align__(8) u16 t[4] = { f2bf(v.x * wq), f2bf(v.y * wq),
                                      f2bf(v.z * wq), f2bf(v.w * wq) };
            *(uint2*)(out + (size_t)(d0 + rr + 16 * i) * 1024 + k0 + cc) = *(const uint2*)t;
        }
    }
}

// ---------------------------------------------------------------------------
// 64x64-tile bf16 MFMA GEMM for W_eff^T: C[m][n] = sum_k A[m,k]*B[n,k],
// M=N=K=1024, z batches slices of 1M elements. 4 waves, each: 4 m-frags x 1
// n-frag. grid (16,16,4) = 1024 blocks -> 4 blocks/CU (vs 1 for 128-tile).
// ---------------------------------------------------------------------------
__global__ __launch_bounds__(256)
void mfma_gemm64(const u16* __restrict__ Asrc, const u16* __restrict__ Bsrc,
                 u16* __restrict__ Cout)
{
    __shared__ u16 As[64 * 64];
    __shared__ u16 Bs[64 * 64];
    const int z = blockIdx.z;
    const u16* A = Asrc + (size_t)z * 1048576;
    const u16* B = Bsrc + (size_t)z * 1048576;
    u16* C = Cout + (size_t)z * 1048576;
    const int tid = threadIdx.x, lane = tid & 63, wave = tid >> 6;
    const int m0 = blockIdx.y * 64, n0 = blockIdx.x * 64;
    const int wn = wave * 16;

    f32x4 acc[4];
    #pragma unroll
    for (int i = 0; i < 4; i++) acc[i] = (f32x4)0.f;

    for (int k0 = 0; k0 < 1024; k0 += 64) {
        __syncthreads();
        #pragma unroll
        for (int it = 0; it < 2; it++) {
            const int c   = it * 256 + tid;
            const int row = c >> 3, j = c & 7;
            const int g   = j ^ (row & 7);
            const u16* ga = A + (size_t)(m0 + row) * 1024 + k0 + g * 8;
            __builtin_amdgcn_global_load_lds(
                (const __attribute__((address_space(1))) u32*)ga,
                (__attribute__((address_space(3))) u32*)&As[(it * 256 + wave * 64) * 8],
                16, 0, 0);
            const u16* gb = B + (size_t)(n0 + row) * 1024 + k0 + g * 8;
            __builtin_amdgcn_global_load_lds(
                (const __attribute__((address_space(1))) u32*)gb,
                (__attribute__((address_space(3))) u32*)&Bs[(it * 256 + wave * 64) * 8],
                16, 0, 0);
        }
        __syncthreads();
        #pragma unroll
        for (int ks = 0; ks < 2; ks++) {
            const int gk = ks * 4 + (lane >> 4);
            const int rn = wn + (lane & 15);
            const int jb = gk ^ (rn & 7);
            const bf16x8 bfr = *(const bf16x8*)&Bs[rn * 64 + jb * 8];
            #pragma unroll
            for (int mi = 0; mi < 4; mi++) {
                const int rm = mi * 16 + (lane & 15);
                const int ja = gk ^ (rm & 7);
                const bf16x8 af = *(const bf16x8*)&As[rm * 64 + ja * 8];
                acc[mi] = __builtin_amdgcn_mfma_f32_16x16x32_bf16(af, bfr, acc[mi], 0, 0, 0);
            }
        }
    }
    const int col_l = lane & 15, row_l = (lane >> 4) * 4;
    #pragma unroll
    for (int mi = 0; mi < 4; mi++)
        #pragma unroll
        for (int i = 0; i < 4; i++)
            C[(size_t)(m0 + mi * 16 + row_l + i) * 1024 + n0 + wn + col_l] = f2bf(acc[mi][i]);
}

// ---------------------------------------------------------------------------
// 128x128-tile bf16 MFMA GEMM, M=8192, N=K=1024, z-batched. XCD-swizzled
// block decode: flat%8 (= XCD under round-robin dispatch) selects an 8-row
// m-group, so each XCD's per-z working set is A 2MB + B 2MB (fits 4MB L2).
// REQUIRES grid == (8, 64, Z).
// ---------------------------------------------------------------------------
template<int OUTBF>
__global__ __launch_bounds__(256)
void mfma_gemm(const u16* __restrict__ Asrc, const u16* __restrict__ Bt,
               void* __restrict__ Cout, size_t astride, size_t bstride, size_t cstride)
{
    __shared__ u16 As[128 * 64];
    __shared__ u16 Bs[128 * 64];
    const int flat = blockIdx.x + 8 * (blockIdx.y + 64 * blockIdx.z);
    const int xcd = flat & 7;
    const int r   = flat >> 3;
    const int nb = r & 7, mlocal = (r >> 3) & 7, zb = r >> 6;
    const int m0 = (xcd * 8 + mlocal) * 128, n0 = nb * 128;

    const u16* A = Asrc + (size_t)zb * astride;
    const u16* B = Bt   + (size_t)zb * bstride;
    const int tid  = threadIdx.x;
    const int lane = tid & 63, wave = tid >> 6;
    const int wm = (wave >> 1) * 64, wn = (wave & 1) * 64;

    f32x4 acc[4][4];
    #pragma unroll
    for (int i = 0; i < 4; i++)
        #pragma unroll
        for (int j = 0; j < 4; j++) acc[i][j] = (f32x4)0.f;

    for (int k0 = 0; k0 < 1024; k0 += 64) {
        __syncthreads();
        #pragma unroll
        for (int it = 0; it < 4; it++) {
            const int c   = it * 256 + tid;
            const int row = c >> 3, j = c & 7;
            const int g   = j ^ (row & 7);
            const u16* ga = A + (size_t)(m0 + row) * 1024 + k0 + g * 8;
            __builtin_amdgcn_global_load_lds(
                (const __attribute__((address_space(1))) u32*)ga,
                (__attribute__((address_space(3))) u32*)&As[(it * 256 + wave * 64) * 8],
                16, 0, 0);
            const u16* gb = B + (size_t)(n0 + row) * 1024 + k0 + g * 8;
            __builtin_amdgcn_global_load_lds(
                (const __attribute__((address_space(1))) u32*)gb,
                (__attribute__((address_space(3))) u32*)&Bs[(it * 256 + wave * 64) * 8],
                16, 0, 0);
        }
        __syncthreads();
        #pragma unroll
        for (int ks = 0; ks < 2; ks++) {
            bf16x8 af[4], bfr[4];
            const int gk = ks * 4 + (lane >> 4);
            #pragma unroll
            for (int mi = 0; mi < 4; mi++) {
                const int rr  = wm + mi * 16 + (lane & 15);
                const int ja = gk ^ (rr & 7);
                af[mi] = *(const bf16x8*)&As[rr * 64 + ja * 8];
                const int rn = wn + mi * 16 + (lane & 15);
                const int jb = gk ^ (rn & 7);
                bfr[mi] = *(const bf16x8*)&Bs[rn * 64 + jb * 8];
            }
            #pragma unroll
            for (int mi = 0; mi < 4; mi++)
                #pragma unroll
                for (int ni = 0; ni < 4; ni++)
                    acc[mi][ni] = __builtin_amdgcn_mfma_f32_16x16x32_bf16(
                        af[mi], bfr[ni], acc[mi][ni], 0, 0, 0);
        }
    }
    // epilogue: C/D layout col=lane&15, row=(lane>>4)*4+reg  [m89-verified]
    const int col_l = lane & 15, row_l = (lane >> 4) * 4;
    if (OUTBF) {
        u16* C = (u16*)Cout + (size_t)zb * cstride;
        #pragma unroll
        for (int mi = 0; mi < 4; mi++)
            #pragma unroll
            for (int ni = 0; ni < 4; ni++)
                #pragma unroll
                for (int i = 0; i < 4; i++) {
                    const int rw  = m0 + wm + mi * 16 + row_l + i;
                    const int cn = n0 + wn + ni * 16 + col_l;
                    C[(size_t)rw * 1024 + cn] = f2bf(acc[mi][ni][i]);
                }
    } else {
        float* C = (float*)Cout + (size_t)zb * cstride;
        #pragma unroll
        for (int mi = 0; mi < 4; mi++)
            #pragma unroll
            for (int ni = 0; ni < 4; ni++)
                #pragma unroll
                for (int i = 0; i < 4; i++) {
                    const int rw  = m0 + wm + mi * 16 + row_l + i;
                    const int cn = n0 + wn + ni * 16 + col_l;
                    C[(size_t)rw * 1024 + cn] = acc[mi][ni][i];
                }
    }
}

// ---------------------------------------------------------------------------
// Decay: one wave per token. dec[t][h] = 1/(1+exp(x.dw_h + b_h)).
// ---------------------------------------------------------------------------
__global__ __launch_bounds__(256)
void decay_kernel(const float* __restrict__ x, const float* __restrict__ dw,
                  const float* __restrict__ db, float* __restrict__ dec)
{
    const int wave = threadIdx.x >> 6, lane = threadIdx.x & 63;
    const int t = blockIdx.x * 4 + wave;
    const float4* x4 = (const float4*)(x + (size_t)t * 1024);
    float4 xv[4];
    #pragma unroll
    for (int i = 0; i < 4; i++) xv[i] = x4[lane + 64 * i];
    float p[16];
    #pragma unroll
    for (int h = 0; h < 16; h++) {
        const float4* w4 = (const float4*)(dw + (size_t)h * 1024);
        float s = 0.f;
        #pragma unroll
        for (int i = 0; i < 4; i++) {
            const float4 wv = w4[lane + 64 * i];
            s = fmaf(xv[i].x, wv.x, fmaf(xv[i].y, wv.y,
                fmaf(xv[i].z, wv.z, fmaf(xv[i].w, wv.w, s))));
        }
        p[h] = s;
    }
    #pragma unroll
    for (int off = 32; off > 0; off >>= 1)
        #pragma unroll
        for (int h = 0; h < 16; h++) p[h] += __shfl_xor(p[h], off);
    if (lane == 0) {
        #pragma unroll
        for (int h = 0; h < 16; h++)
            dec[(size_t)t * 16 + h] = 1.f / (1.f + __expf(p[h] + db[h]));
    }
}

// ---------------------------------------------------------------------------
// Chunk-parallel scan, 3 phases. s_t = a_t*s_{t-1} + sigmoid(g)*k*v; out=q*s.
// ---------------------------------------------------------------------------
__global__ __launch_bounds__(64)
void scan1(const u16* __restrict__ Kq, const u16* __restrict__ Vq, const u16* __restrict__ Gq,
           const float* __restrict__ dec, float* __restrict__ Lc, float* __restrict__ Pc)
{
    const int c = blockIdx.x & 31, h = (blockIdx.x >> 5) & 15, b = blockIdx.x >> 9;
    const int d = threadIdx.x;
    const size_t t0 = (size_t)b * SEQ + c * CT;
    const size_t base = t0 * 1024 + h * 64 + d;
    const u16* kp = Kq + base;
    const u16* vp = Vq + base;
    const u16* gp = Gq + base;
    const float* dp = dec + t0 * 16 + h;
    float s = 0.f, P = 1.f;
    #pragma unroll 4
    for (int t = 0; t < CT; t++) {
        const size_t o = (size_t)t * 1024;
        const float a  = dp[t * 16];
        const float kv = b2f(kp[o]) * b2f(vp[o]) * sigf(b2f(gp[o]));
        s = fmaf(a, s, kv);
        P *= a;
    }
    const int ci = (b * 16 + h) * NC + c;
    Lc[(size_t)ci * 64 + d] = s;
    if (d == 0) Pc[ci] = P;
}

__global__ __launch_bounds__(64)
void scan2(const float* __restrict__ Lc, const float* __restrict__ Pc, float* __restrict__ Ic)
{
    const int bh = blockIdx.x, d = threadIdx.x;
    float S = 0.f;
    for (int c = 0; c < NC; c++) {
        const int ci = bh * NC + c;
        Ic[(size_t)ci * 64 + d] = S;
        S = fmaf(Pc[ci], S, Lc[(size_t)ci * 64 + d]);
    }
}

__global__ __launch_bounds__(64)
void scan3(const u16* __restrict__ Qq, const u16* __restrict__ Kq,
           const u16* __restrict__ Vq, const u16* __restrict__ Gq,
           const float* __restrict__ dec, const float* __restrict__ Ic,
           u16* __restrict__ attb)
{
    const int c = blockIdx.x & 31, h = (blockIdx.x >> 5) & 15, b = blockIdx.x >> 9;
    const int d = threadIdx.x;
    const size_t t0 = (size_t)b * SEQ + c * CT;
    const size_t base = t0 * 1024 + h * 64 + d;
    const u16* qp = Qq + base;
    const u16* kp = Kq + base;
    const u16* vp = Vq + base;
    const u16* gp = Gq + base;
    const float* dp = dec + t0 * 16 + h;
    const int ci = (b * 16 + h) * NC + c;
    float s = Ic[(size_t)ci * 64 + d];
    #pragma unroll 4
    for (int t = 0; t < CT; t++) {
        const size_t o = (size_t)t * 1024;
        const float a  = dp[t * 16];
        const float kv = b2f(kp[o]) * b2f(vp[o]) * sigf(b2f(gp[o]));
        s = fmaf(a, s, kv);
        attb[base + o] = f2bf(b2f(qp[o]) * s);
    }
}

// ---------------------------------------------------------------------------
// RMSNorm * rms_w * sigmoid(gpre) -> bf16, one block per token (bf16 in)
// ---------------------------------------------------------------------------
__global__ __launch_bounds__(256)
void rms_gate(const u16* __restrict__ attb, const u16* __restrict__ gpre,
              const float* __restrict__ rmsw, u16* __restrict__ o)
{
    const size_t t = blockIdx.x;
    const int tid = threadIdx.x;
    const ushort4 a4 = ((const ushort4*)(attb + t * 1024))[tid];
    const float ax = b2f(a4.x), ay = b2f(a4.y), az = b2f(a4.z), aw = b2f(a4.w);
    float ss = ax*ax + ay*ay + az*az + aw*aw;
    #pragma unroll
    for (int d = 32; d > 0; d >>= 1) ss += __shfl_down(ss, d);
    __shared__ float red[4];
    if ((tid & 63) == 0) red[tid >> 6] = ss;
    __syncthreads();
    const float tot = red[0] + red[1] + red[2] + red[3];
    const float scale = rsqrtf(tot * (1.0f / 1024.0f) + 1.1920929e-7f);
    const ushort4 g4 = ((const ushort4*)(gpre + t * 1024))[tid];
    const float4 w   = ((const float4*)rmsw)[tid];
    __align__(8) u16 r[4];
    r[0] = f2bf(ax * scale * w.x * sigf(b2f(g4.x)));
    r[1] = f2bf(ay * scale * w.y * sigf(b2f(g4.y)));
    r[2] = f2bf(az * scale * w.z * sigf(b2f(g4.z)));
    r[3] = f2bf(aw * scale * w.w * sigf(b2f(g4.w)));
    ((uint2*)(o + t * 1024))[tid] = *(const uint2*)r;
}

// ---------------------------------------------------------------------------
extern "C" void kernel_launch(void* const* d_in, const int* in_sizes, int n_in,
                              void* d_out, int out_size, void* d_ws, size_t ws_size,
                              hipStream_t stream)
{
    const float* x    = (const float*)d_in[0];
    const float* qU   = (const float*)d_in[1];
    const float* qV   = (const float*)d_in[2];
    const float* kU   = (const float*)d_in[3];
    const float* kV   = (const float*)d_in[4];
    const float* vU   = (const float*)d_in[5];
    const float* vV   = (const float*)d_in[6];
    const float* ql   = (const float*)d_in[7];
    const float* kl   = (const float*)d_in[8];
    const float* vl   = (const float*)d_in[9];
    const float* gl   = (const float*)d_in[10];
    const float* dw   = (const float*)d_in[11];
    const float* db   = (const float*)d_in[12];
    const float* ogw  = (const float*)d_in[13];
    const float* opw  = (const float*)d_in[14];
    const float* rmsw = (const float*)d_in[15];

    // workspace layout (byte offsets, ~148.4 MB total)
    char* w = (char*)d_ws;
    float* dec  = (float*)(w + 0);           // 512 KB
    u16*   WT   = (u16*)  (w + 524288);      // 5 slices x 1M bf16 = 10 MB (slice4 = ogwb)
    u16*   xb   = (u16*)  (w + 11010048);    // 16 MB
    u16*   opwb = (u16*)  (w + 27787264);    // 2 MB
    u16*   QKVG = (u16*)  (w + 29884416);    // 5 slices x 8M bf16 = 80 MB (q,k,v,g,gpre)
    u16*   RMSO = (u16*)  (w + 113770496);   // 16 MB
    u16*   ATTb = (u16*)  (w + 130547712);   // 16 MB
    float* Lc   = (float*)(w + 147324928);   // 512 KB
    float* Ic   = (float*)(w + 147849216);   // 512 KB
    float* Pc   = (float*)(w + 148373504);   // 8 KB
    // gU/gVT alias the QKVG region (consumed by weff-gemm before QKVG written)
    u16*   gU   = QKVG;                      // 8 MB
    u16*   gVT  = QKVG + 4194304;            // 8 MB
    u16*   ogwb = WT + 4 * 1048576;          // WT slice 4
    u16*   GPRE = QKVG + 4 * 8388608;        // QKVG slice 4

    // 1. casts (x, out_gate_w -> WT slice4, out_proj_w)
    f2b_all<<<10240, 256, 0, stream>>>(x, ogw, opw, xb, ogwb, opwb);

    // 2. gather selected prims (topk inline): gU (w folded), gVT (transposed)
    gather_all<<<dim3(16, 16, 8), 256, 0, stream>>>(qU, kU, vU, qV, kV, vV,
                                                    ql, kl, vl, gl, gU, gVT);

    // 3. WT[p][o][d] = sum_k gVT[p][o,k] * gU[p][d,k]  (= W_eff^T)
    mfma_gemm64<<<dim3(16, 16, 4), 256, 0, stream>>>(gVT, gU, WT);

    // 4. q,k,v,gate,gpre = x @ {W_eff_p, out_gate_w}^T -> bf16, z=5 batch
    mfma_gemm<1><<<dim3(8, 64, 5), 256, 0, stream>>>(xb, WT, QKVG,
                                                     (size_t)0, (size_t)1048576,
                                                     (size_t)8388608);

    // 5. decay (fp32 path — exponential-sensitivity kept full precision)
    decay_kernel<<<2048, 256, 0, stream>>>(x, dw, db, dec);

    // 6-8. chunk-parallel scan
    scan1<<<2048, 64, 0, stream>>>(QKVG + 8388608, QKVG + 16777216, QKVG + 25165824,
                                   dec, Lc, Pc);
    scan2<<<64, 64, 0, stream>>>(Lc, Pc, Ic);
    scan3<<<2048, 64, 0, stream>>>(QKVG, QKVG + 8388608, QKVG + 16777216, QKVG + 25165824,
                                   dec, Ic, ATTb);

    // 9. rmsnorm * gate
    rms_gate<<<8192, 256, 0, stream>>>(ATTb, GPRE, rmsw, RMSO);

    // 10. final: rmso @ out_proj_w^T -> fp32 d_out
    mfma_gemm<0><<<dim3(8, 64, 1), 256, 0, stream>>>(RMSO, opwb, (float*)d_out, 0, 0, 0);
}

// Round 5
// 397.819 us; speedup vs baseline: 5.4016x; 1.0349x over previous
//
#include <hip/hip_runtime.h>
#include <hip/hip_bf16.h>

// Problem constants (B=4, S=2048, D_MODEL=1024, H=16, DH=64, RANK=256, NPRIM=16, top_k=4)
#define TOK 8192
#define SEQ 2048
#define CT  32          // scan chunk length
#define NC  64          // chunks per sequence

typedef __attribute__((ext_vector_type(8))) short bf16x8;   // 8 bf16 = 4 VGPRs
typedef __attribute__((ext_vector_type(4))) float f32x4;
typedef unsigned short u16;
typedef unsigned int   u32;

__device__ __forceinline__ u16 f2bf(float f) {
    u32 u = __float_as_uint(f);
    u = (u + 0x7FFFu + ((u >> 16) & 1u)) >> 16;   // RNE
    return (u16)u;
}
__device__ __forceinline__ float b2f(u16 h) { return __uint_as_float(((u32)h) << 16); }
__device__ __forceinline__ float sigf(float z) { return 1.f / (1.f + __expf(-z)); }

// Top-4 of 16 logits + softmax over the kept 4 (== softmax->topk->renorm, exact).
__device__ __forceinline__ void topk4(const float* __restrict__ lg, int* idx, float* wv)
{
    float v[16];
    #pragma unroll
    for (int i = 0; i < 16; i++) v[i] = lg[i];
    bool used[16];
    #pragma unroll
    for (int i = 0; i < 16; i++) used[i] = false;
    float val[4];
    #pragma unroll
    for (int k = 0; k < 4; k++) {
        int bi = 0; float bv = -3.0e38f;
        #pragma unroll
        for (int i = 0; i < 16; i++)
            if (!used[i] && v[i] > bv) { bv = v[i]; bi = i; }
        used[bi] = true; idx[k] = bi; val[k] = bv;
    }
    float e[4], s = 0.f;
    #pragma unroll
    for (int k = 0; k < 4; k++) { e[k] = expf(val[k] - val[0]); s += e[k]; }
    #pragma unroll
    for (int k = 0; k < 4; k++) wv[k] = e[k] / s;
}

// ---------------------------------------------------------------------------
// prep: one dispatch doing three independent jobs, branch by block range.
//   [0, 10240)      : fp32->bf16 casts of x / out_gate_w / out_proj_w
//   [10240, 12288)  : gather selected prims -> gU (w folded), gVT (transposed)
//   [12288, 14336)  : decay pre-activation dec[t][h] = 1/(1+exp(x.dw_h+b_h))
// ---------------------------------------------------------------------------
__global__ __launch_bounds__(256)
void prep(const float* __restrict__ x, const float* __restrict__ ogw,
          const float* __restrict__ opw,
          const float* __restrict__ qU, const float* __restrict__ kU,
          const float* __restrict__ vU,
          const float* __restrict__ qV, const float* __restrict__ kV,
          const float* __restrict__ vV,
          const float* __restrict__ ql, const float* __restrict__ kl,
          const float* __restrict__ vl, const float* __restrict__ gl,
          const float* __restrict__ dw, const float* __restrict__ db,
          u16* __restrict__ xb, u16* __restrict__ ogwb, u16* __restrict__ opwb,
          u16* __restrict__ gU, u16* __restrict__ gVT, float* __restrict__ dec)
{
    const int blk = blockIdx.x;
    const int tid = threadIdx.x;

    if (blk < 10240) {
        // ---- bulk bf16 casts: 2621440 float4-groups ----
        const int i = blk * 256 + tid;
        const float* src; u16* dst; int off;
        if (i < 2097152)      { src = x;   dst = xb;   off = i; }
        else if (i < 2359296) { src = ogw; dst = ogwb; off = i - 2097152; }
        else                  { src = opw; dst = opwb; off = i - 2359296; }
        const float4 v = ((const float4*)src)[off];
        __align__(8) u16 t[4] = { f2bf(v.x), f2bf(v.y), f2bf(v.z), f2bf(v.w) };
        ((uint2*)dst)[off] = *(const uint2*)t;
        return;
    }
    if (blk < 12288) {
        // ---- gather (topk inline, exact) ----
        const int local = blk - 10240;
        const int z = local >> 8;              // 0..7
        const int bx = local & 15, by = (local >> 4) & 15;
        const int p = z & 3;
        const float* lg = (p == 0) ? ql : (p == 1) ? kl : (p == 2) ? vl : gl;
        int idx[4]; float wsel[4];
        topk4(lg, idx, wsel);

        if (z < 4) {
            // V^T gather: gVT[p][o][k=s*256+r] = V_sel[s][r][o]
            const float* V = (p == 0) ? qV : (p == 1) ? kV : vV;
            const int o0 = bx * 64, k0 = by * 64;
            const int s = k0 >> 8, r0 = k0 & 255;
            const float* Vb = V + (size_t)idx[s] * (256 * 1024);
            __shared__ float tile[64][68];
            const int rr = tid >> 4, cc = (tid & 15) << 2;
            #pragma unroll
            for (int i = 0; i < 4; i++) {
                const float4 v = *(const float4*)(Vb + (size_t)(r0 + rr + 16 * i) * 1024 + o0 + cc);
                *(float4*)&tile[rr + 16 * i][cc] = v;
            }
            __syncthreads();
            const int oo = tid >> 4, kk = (tid & 15) << 2;
            u16* out = gVT + (size_t)p * 1048576;
            #pragma unroll
            for (int i = 0; i < 4; i++) {
                __align__(8) u16 t[4];
                #pragma unroll
                for (int j = 0; j < 4; j++) t[j] = f2bf(tile[kk + j][oo + 16 * i]);
                *(uint2*)(out + (size_t)(o0 + oo + 16 * i) * 1024 + k0 + kk) = *(const uint2*)t;
            }
        } else {
            // U gather: gU[p][d][k=s*256+r] = w_s * U_sel[s][d][r]
            const float* U = (p == 0) ? qU : (p == 1) ? kU : vU;
            const int d0 = bx * 64, k0 = by * 64;
            const int s = k0 >> 8, r0 = k0 & 255;
            const float* Ub = U + (size_t)idx[s] * (1024 * 256);
            const float wq = wsel[s];
            u16* out = gU + (size_t)p * 1048576;
            const int rr = tid >> 4, cc = (tid & 15) << 2;
            #pragma unroll
            for (int i = 0; i < 4; i++) {
                const float4 v = *(const float4*)(Ub + (size_t)(d0 + rr + 16 * i) * 256 + r0 + cc);
                __align__(8) u16 t[4] = { f2bf(v.x * wq), f2bf(v.y * wq),
                                          f2bf(v.z * wq), f2bf(v.w * wq) };
                *(uint2*)(out + (size_t)(d0 + rr + 16 * i) * 1024 + k0 + cc) = *(const uint2*)t;
            }
        }
        return;
    }
    // ---- decay: one wave per token ----
    {
        const int tg = blk - 12288;
        const int wave = tid >> 6, lane = tid & 63;
        const int t = tg * 4 + wave;
        const float4* x4 = (const float4*)(x + (size_t)t * 1024);
        float4 xv[4];
        #pragma unroll
        for (int i = 0; i < 4; i++) xv[i] = x4[lane + 64 * i];
        float p[16];
        #pragma unroll
        for (int h = 0; h < 16; h++) {
            const float4* w4 = (const float4*)(dw + (size_t)h * 1024);
            float s = 0.f;
            #pragma unroll
            for (int i = 0; i < 4; i++) {
                const float4 wv = w4[lane + 64 * i];
                s = fmaf(xv[i].x, wv.x, fmaf(xv[i].y, wv.y,
                    fmaf(xv[i].z, wv.z, fmaf(xv[i].w, wv.w, s))));
            }
            p[h] = s;
        }
        #pragma unroll
        for (int off = 32; off > 0; off >>= 1)
            #pragma unroll
            for (int h = 0; h < 16; h++) p[h] += __shfl_xor(p[h], off);
        if (lane == 0) {
            #pragma unroll
            for (int h = 0; h < 16; h++)
                dec[(size_t)t * 16 + h] = 1.f / (1.f + __expf(p[h] + db[h]));
        }
    }
}

// ---------------------------------------------------------------------------
// 64x64-tile bf16 MFMA GEMM for W_eff^T: C[m][n] = sum_k A[m,k]*B[n,k],
// M=N=K=1024, z batches slices of 1M elements. grid (16,16,4) -> 4 blocks/CU.
// ---------------------------------------------------------------------------
__global__ __launch_bounds__(256)
void mfma_gemm64(const u16* __restrict__ Asrc, const u16* __restrict__ Bsrc,
                 u16* __restrict__ Cout)
{
    __shared__ u16 As[64 * 64];
    __shared__ u16 Bs[64 * 64];
    const int z = blockIdx.z;
    const u16* A = Asrc + (size_t)z * 1048576;
    const u16* B = Bsrc + (size_t)z * 1048576;
    u16* C = Cout + (size_t)z * 1048576;
    const int tid = threadIdx.x, lane = tid & 63, wave = tid >> 6;
    const int m0 = blockIdx.y * 64, n0 = blockIdx.x * 64;
    const int wn = wave * 16;

    f32x4 acc[4];
    #pragma unroll
    for (int i = 0; i < 4; i++) acc[i] = (f32x4)0.f;

    for (int k0 = 0; k0 < 1024; k0 += 64) {
        __syncthreads();
        #pragma unroll
        for (int it = 0; it < 2; it++) {
            const int c   = it * 256 + tid;
            const int row = c >> 3, j = c & 7;
            const int g   = j ^ (row & 7);
            const u16* ga = A + (size_t)(m0 + row) * 1024 + k0 + g * 8;
            __builtin_amdgcn_global_load_lds(
                (const __attribute__((address_space(1))) u32*)ga,
                (__attribute__((address_space(3))) u32*)&As[(it * 256 + wave * 64) * 8],
                16, 0, 0);
            const u16* gb = B + (size_t)(n0 + row) * 1024 + k0 + g * 8;
            __builtin_amdgcn_global_load_lds(
                (const __attribute__((address_space(1))) u32*)gb,
                (__attribute__((address_space(3))) u32*)&Bs[(it * 256 + wave * 64) * 8],
                16, 0, 0);
        }
        __syncthreads();
        #pragma unroll
        for (int ks = 0; ks < 2; ks++) {
            const int gk = ks * 4 + (lane >> 4);
            const int rn = wn + (lane & 15);
            const int jb = gk ^ (rn & 7);
            const bf16x8 bfr = *(const bf16x8*)&Bs[rn * 64 + jb * 8];
            #pragma unroll
            for (int mi = 0; mi < 4; mi++) {
                const int rm = mi * 16 + (lane & 15);
                const int ja = gk ^ (rm & 7);
                const bf16x8 af = *(const bf16x8*)&As[rm * 64 + ja * 8];
                acc[mi] = __builtin_amdgcn_mfma_f32_16x16x32_bf16(af, bfr, acc[mi], 0, 0, 0);
            }
        }
    }
    const int col_l = lane & 15, row_l = (lane >> 4) * 4;
    #pragma unroll
    for (int mi = 0; mi < 4; mi++)
        #pragma unroll
        for (int i = 0; i < 4; i++)
            C[(size_t)(m0 + mi * 16 + row_l + i) * 1024 + n0 + wn + col_l] = f2bf(acc[mi][i]);
}

// ---------------------------------------------------------------------------
// 128x128-tile bf16 MFMA GEMM, M=8192, N=K=1024, z-batched. XCD-swizzled
// block decode (flat%8 = XCD under round-robin) pins an 8-row m-group per
// XCD: per-z working set A 2MB + B 2MB fits the 4MB XCD L2.
// REQUIRES grid == (8, 64, Z).
// ---------------------------------------------------------------------------
template<int OUTBF>
__global__ __launch_bounds__(256)
void mfma_gemm(const u16* __restrict__ Asrc, const u16* __restrict__ Bt,
               void* __restrict__ Cout, size_t astride, size_t bstride, size_t cstride)
{
    __shared__ u16 As[128 * 64];
    __shared__ u16 Bs[128 * 64];
    const int flat = blockIdx.x + 8 * (blockIdx.y + 64 * blockIdx.z);
    const int xcd = flat & 7;
    const int r   = flat >> 3;
    const int nb = r & 7, mlocal = (r >> 3) & 7, zb = r >> 6;
    const int m0 = (xcd * 8 + mlocal) * 128, n0 = nb * 128;

    const u16* A = Asrc + (size_t)zb * astride;
    const u16* B = Bt   + (size_t)zb * bstride;
    const int tid  = threadIdx.x;
    const int lane = tid & 63, wave = tid >> 6;
    const int wm = (wave >> 1) * 64, wn = (wave & 1) * 64;

    f32x4 acc[4][4];
    #pragma unroll
    for (int i = 0; i < 4; i++)
        #pragma unroll
        for (int j = 0; j < 4; j++) acc[i][j] = (f32x4)0.f;

    for (int k0 = 0; k0 < 1024; k0 += 64) {
        __syncthreads();
        #pragma unroll
        for (int it = 0; it < 4; it++) {
            const int c   = it * 256 + tid;
            const int row = c >> 3, j = c & 7;
            const int g   = j ^ (row & 7);
            const u16* ga = A + (size_t)(m0 + row) * 1024 + k0 + g * 8;
            __builtin_amdgcn_global_load_lds(
                (const __attribute__((address_space(1))) u32*)ga,
                (__attribute__((address_space(3))) u32*)&As[(it * 256 + wave * 64) * 8],
                16, 0, 0);
            const u16* gb = B + (size_t)(n0 + row) * 1024 + k0 + g * 8;
            __builtin_amdgcn_global_load_lds(
                (const __attribute__((address_space(1))) u32*)gb,
                (__attribute__((address_space(3))) u32*)&Bs[(it * 256 + wave * 64) * 8],
                16, 0, 0);
        }
        __syncthreads();
        #pragma unroll
        for (int ks = 0; ks < 2; ks++) {
            bf16x8 af[4], bfr[4];
            const int gk = ks * 4 + (lane >> 4);
            #pragma unroll
            for (int mi = 0; mi < 4; mi++) {
                const int rr  = wm + mi * 16 + (lane & 15);
                const int ja = gk ^ (rr & 7);
                af[mi] = *(const bf16x8*)&As[rr * 64 + ja * 8];
                const int rn = wn + mi * 16 + (lane & 15);
                const int jb = gk ^ (rn & 7);
                bfr[mi] = *(const bf16x8*)&Bs[rn * 64 + jb * 8];
            }
            #pragma unroll
            for (int mi = 0; mi < 4; mi++)
                #pragma unroll
                for (int ni = 0; ni < 4; ni++)
                    acc[mi][ni] = __builtin_amdgcn_mfma_f32_16x16x32_bf16(
                        af[mi], bfr[ni], acc[mi][ni], 0, 0, 0);
        }
    }
    // epilogue: C/D layout col=lane&15, row=(lane>>4)*4+reg  [m89-verified]
    const int col_l = lane & 15, row_l = (lane >> 4) * 4;
    if (OUTBF) {
        u16* C = (u16*)Cout + (size_t)zb * cstride;
        #pragma unroll
        for (int mi = 0; mi < 4; mi++)
            #pragma unroll
            for (int ni = 0; ni < 4; ni++)
                #pragma unroll
                for (int i = 0; i < 4; i++) {
                    const int rw  = m0 + wm + mi * 16 + row_l + i;
                    const int cn = n0 + wn + ni * 16 + col_l;
                    C[(size_t)rw * 1024 + cn] = f2bf(acc[mi][ni][i]);
                }
    } else {
        float* C = (float*)Cout + (size_t)zb * cstride;
        #pragma unroll
        for (int mi = 0; mi < 4; mi++)
            #pragma unroll
            for (int ni = 0; ni < 4; ni++)
                #pragma unroll
                for (int i = 0; i < 4; i++) {
                    const int rw  = m0 + wm + mi * 16 + row_l + i;
                    const int cn = n0 + wn + ni * 16 + col_l;
                    C[(size_t)rw * 1024 + cn] = acc[mi][ni][i];
                }
    }
}

// ---------------------------------------------------------------------------
// Chunk-parallel scan, CT=32, NC=64. s_t = a_t*s_{t-1} + sigmoid(g)*k*v.
// scan1: local scan per chunk; writes rounded kv product (kvb), chunk-local
// state Lc[ci][d] and decay product Pc[ci].
// ---------------------------------------------------------------------------
__global__ __launch_bounds__(64)
void scan1(const u16* __restrict__ Kq, const u16* __restrict__ Vq, const u16* __restrict__ Gq,
           const float* __restrict__ dec, u16* __restrict__ kvb,
           float* __restrict__ Lc, float* __restrict__ Pc)
{
    const int c = blockIdx.x & (NC - 1), h = (blockIdx.x >> 6) & 15, b = blockIdx.x >> 10;
    const int d = threadIdx.x;
    const size_t t0 = (size_t)b * SEQ + c * CT;
    const size_t base = t0 * 1024 + h * 64 + d;
    const u16* kp = Kq + base;
    const u16* vp = Vq + base;
    const u16* gp = Gq + base;
    const float* dp = dec + t0 * 16 + h;
    float s = 0.f, P = 1.f;
    #pragma unroll 4
    for (int t = 0; t < CT; t++) {
        const size_t o = (size_t)t * 1024;
        const float a  = dp[t * 16];
        const u16 kq = f2bf(b2f(kp[o]) * b2f(vp[o]) * sigf(b2f(gp[o])));
        kvb[base + o] = kq;
        s = fmaf(a, s, b2f(kq));
        P *= a;
    }
    const int ci = (b * 16 + h) * NC + c;
    Lc[(size_t)ci * 64 + d] = s;
    if (d == 0) Pc[ci] = P;
}

// scan2 folded into scan3: each block combines its chunk prefix inline.
__global__ __launch_bounds__(64)
void scan3(const u16* __restrict__ Qq, const u16* __restrict__ kvb,
           const float* __restrict__ dec,
           const float* __restrict__ Lc, const float* __restrict__ Pc,
           u16* __restrict__ attb)
{
    const int c = blockIdx.x & (NC - 1), h = (blockIdx.x >> 6) & 15, b = blockIdx.x >> 10;
    const int d = threadIdx.x;
    const size_t t0 = (size_t)b * SEQ + c * CT;
    const size_t base = t0 * 1024 + h * 64 + d;
    const u16* qp = Qq + base;
    const u16* kp = kvb + base;
    const float* dp = dec + t0 * 16 + h;

    // inline prefix combine over earlier chunks of this (b,h)
    const int ci0 = (b * 16 + h) * NC;
    float s = 0.f;
    for (int cc = 0; cc < c; cc++)
        s = fmaf(Pc[ci0 + cc], s, Lc[(size_t)(ci0 + cc) * 64 + d]);

    #pragma unroll 4
    for (int t = 0; t < CT; t++) {
        const size_t o = (size_t)t * 1024;
        const float a  = dp[t * 16];
        s = fmaf(a, s, b2f(kp[o]));
        attb[base + o] = f2bf(b2f(qp[o]) * s);
    }
}

// ---------------------------------------------------------------------------
// RMSNorm * rms_w * sigmoid(gpre) -> bf16, one block per token (bf16 in)
// ---------------------------------------------------------------------------
__global__ __launch_bounds__(256)
void rms_gate(const u16* __restrict__ attb, const u16* __restrict__ gpre,
              const float* __restrict__ rmsw, u16* __restrict__ o)
{
    const size_t t = blockIdx.x;
    const int tid = threadIdx.x;
    const ushort4 a4 = ((const ushort4*)(attb + t * 1024))[tid];
    const float ax = b2f(a4.x), ay = b2f(a4.y), az = b2f(a4.z), aw = b2f(a4.w);
    float ss = ax*ax + ay*ay + az*az + aw*aw;
    #pragma unroll
    for (int d = 32; d > 0; d >>= 1) ss += __shfl_down(ss, d);
    __shared__ float red[4];
    if ((tid & 63) == 0) red[tid >> 6] = ss;
    __syncthreads();
    const float tot = red[0] + red[1] + red[2] + red[3];
    const float scale = rsqrtf(tot * (1.0f / 1024.0f) + 1.1920929e-7f);
    const ushort4 g4 = ((const ushort4*)(gpre + t * 1024))[tid];
    const float4 w   = ((const float4*)rmsw)[tid];
    __align__(8) u16 r[4];
    r[0] = f2bf(ax * scale * w.x * sigf(b2f(g4.x)));
    r[1] = f2bf(ay * scale * w.y * sigf(b2f(g4.y)));
    r[2] = f2bf(az * scale * w.z * sigf(b2f(g4.z)));
    r[3] = f2bf(aw * scale * w.w * sigf(b2f(g4.w)));
    ((uint2*)(o + t * 1024))[tid] = *(const uint2*)r;
}

// ---------------------------------------------------------------------------
extern "C" void kernel_launch(void* const* d_in, const int* in_sizes, int n_in,
                              void* d_out, int out_size, void* d_ws, size_t ws_size,
                              hipStream_t stream)
{
    const float* x    = (const float*)d_in[0];
    const float* qU   = (const float*)d_in[1];
    const float* qV   = (const float*)d_in[2];
    const float* kU   = (const float*)d_in[3];
    const float* kV   = (const float*)d_in[4];
    const float* vU   = (const float*)d_in[5];
    const float* vV   = (const float*)d_in[6];
    const float* ql   = (const float*)d_in[7];
    const float* kl   = (const float*)d_in[8];
    const float* vl   = (const float*)d_in[9];
    const float* gl   = (const float*)d_in[10];
    const float* dw   = (const float*)d_in[11];
    const float* db   = (const float*)d_in[12];
    const float* ogw  = (const float*)d_in[13];
    const float* opw  = (const float*)d_in[14];
    const float* rmsw = (const float*)d_in[15];

    // workspace layout (byte offsets, ~165.2 MB total)
    char* w = (char*)d_ws;
    float* dec  = (float*)(w + 0);           // 512 KB
    u16*   WT   = (u16*)  (w + 524288);      // 5 slices x 2 MB (slice4 = ogwb)
    u16*   xb   = (u16*)  (w + 11010048);    // 16 MB
    u16*   opwb = (u16*)  (w + 27787264);    // 2 MB
    u16*   QKVG = (u16*)  (w + 29884416);    // 5 slices x 16 MB (q,k,v,g,gpre)
    u16*   RMSO = (u16*)  (w + 113770496);   // 16 MB
    u16*   ATTb = (u16*)  (w + 130547712);   // 16 MB
    u16*   kvb  = (u16*)  (w + 147324928);   // 16 MB
    float* Lc   = (float*)(w + 164102144);   // 1 MB
    float* Pc   = (float*)(w + 165150720);   // 16 KB
    // gU/gVT alias the QKVG region (consumed by weff-gemm before QKVG written)
    u16*   gU   = QKVG;                      // 8 MB
    u16*   gVT  = QKVG + 4194304;            // 8 MB
    u16*   ogwb = WT + 4 * 1048576;          // WT slice 4
    u16*   GPRE = QKVG + 4 * 8388608;        // QKVG slice 4

    // 1. prep: casts + prim gathers + decay (independent jobs, one dispatch)
    prep<<<14336, 256, 0, stream>>>(x, ogw, opw, qU, kU, vU, qV, kV, vV,
                                    ql, kl, vl, gl, dw, db,
                                    xb, ogwb, opwb, gU, gVT, dec);

    // 2. WT[p][o][d] = sum_k gVT[p][o,k] * gU[p][d,k]  (= W_eff^T)
    mfma_gemm64<<<dim3(16, 16, 4), 256, 0, stream>>>(gVT, gU, WT);

    // 3. q,k,v,gate,gpre = x @ {W_eff_p, out_gate_w}^T -> bf16, z=5 batch
    mfma_gemm<1><<<dim3(8, 64, 5), 256, 0, stream>>>(xb, WT, QKVG,
                                                     (size_t)0, (size_t)1048576,
                                                     (size_t)8388608);

    // 4-5. chunk-parallel scan (prefix combine inlined in scan3)
    scan1<<<4096, 64, 0, stream>>>(QKVG + 8388608, QKVG + 16777216, QKVG + 25165824,
                                   dec, kvb, Lc, Pc);
    scan3<<<4096, 64, 0, stream>>>(QKVG, kvb, dec, Lc, Pc, ATTb);

    // 6. rmsnorm * gate
    rms_gate<<<8192, 256, 0, stream>>>(ATTb, GPRE, rmsw, RMSO);

    // 7. final: rmso @ out_proj_w^T -> fp32 d_out
    mfma_gemm<0><<<dim3(8, 64, 1), 256, 0, stream>>>(RMSO, opwb, (float*)d_out, 0, 0, 0);
}